// Round 1
// baseline (265.525 us; speedup 1.0000x reference)
//
#include <hip/hip_runtime.h>
#include <math.h>

// Problem constants
#define BB 16
#define NN 1024
#define DD 256
#define HH 8
#define DHH 32
#define KNBR 16
#define MM (BB*NN)   // 16384 tokens

// ---------------- workspace layout (bytes) ----------------
// flag | xpe (aliased by ao) | q | k | v | idx
#define OFF_FLAG 0
#define OFF_XPE  ((size_t)256)
#define OFF_Q    (OFF_XPE + (size_t)MM*DD*4)
#define OFF_K    (OFF_Q   + (size_t)MM*DD*4)
#define OFF_V    (OFF_K   + (size_t)MM*DD*4)
#define OFF_AO   OFF_XPE   // attn-out reuses xpe region (xpe dead after QKV gemm)
#define OFF_IDX  (OFF_V   + (size_t)MM*DD*4)
#define WS_NEED  (OFF_IDX + (size_t)MM*KNBR*4)

// ---------------- mask format detection ----------------
// flag: 0 = 4-byte elements (int32 or float32; nonzero word == valid)
//       1 = 1-byte elements (uint8 bool)
__global__ void detect_mask_kernel(const unsigned* __restrict__ mraw, int* __restrict__ flag) {
    __shared__ int s_u8, s_f32;
    if (threadIdx.x == 0) { s_u8 = 0; s_f32 = 0; }
    __syncthreads();
    int u8 = 0, f32 = 0;
    for (int i = threadIdx.x; i < 4096; i += 256) {   // 16 KB: valid for every format
        unsigned w = mraw[i];
        if (w == 0x3f800000u) f32 = 1;
        else if (w > 1u) u8 = 1;
    }
    if (u8)  atomicOr(&s_u8, 1);
    if (f32) atomicOr(&s_f32, 1);
    __syncthreads();
    if (threadIdx.x == 0) *flag = (s_f32 ? 0 : (s_u8 ? 1 : 0));
}

__device__ __forceinline__ int get_valid(const void* m, int i, int u8) {
    if (u8) return ((const unsigned char*)m)[i] != 0;
    return ((const unsigned*)m)[i] != 0u;   // covers int32 and float32 (1.0f != 0)
}

// ---------------- PE + (x + pe) ----------------
// pe channels [0,128) from y = xpos[...,1]; [128,256) from x = xpos[...,0]
// within group: j = g>>1, theta = pos * 2pi / 10000^(j/64); even->sin, odd->cos
__global__ __launch_bounds__(256) void pe_xpe_kernel(
    const float* __restrict__ x, const float* __restrict__ xpos,
    const void* __restrict__ mask, const int* __restrict__ flag,
    float* __restrict__ xpe) {
    int t = blockIdx.x;
    int c = threadIdx.x;
    int u8 = *flag;
    int valid = get_valid(mask, t, u8);
    float pos = xpos[(size_t)t*3 + ((c < 128) ? 1 : 0)];
    int g = c & 127;
    int j = g >> 1;
    // 2*pi / 10000^(j/64) = 2*pi * 2^(-j * log2(10000)/64)
    float recip = 6.2831853071795864f * exp2f(-(float)j * 0.20762050593045952f);
    float th = pos * recip;
    float pe = (g & 1) ? cosf(th) : sinf(th);
    if (!valid) pe = 0.f;
    size_t o = (size_t)t*DD + c;
    xpe[o] = x[o] + pe;
}

// ---------------- KNN: one wave per query row ----------------
__global__ __launch_bounds__(256) void knn_kernel(const float* __restrict__ xpos,
                                                  int* __restrict__ idxout) {
    __shared__ float sx[NN], sy[NN], sz[NN], sq[NN];
    int b = blockIdx.y;
    for (int i = threadIdx.x; i < NN; i += 256) {
        float px = xpos[((size_t)b*NN + i)*3 + 0];
        float py = xpos[((size_t)b*NN + i)*3 + 1];
        float pz = xpos[((size_t)b*NN + i)*3 + 2];
        sx[i] = px; sy[i] = py; sz[i] = pz;
        sq[i] = px*px + py*py + pz*pz;
    }
    __syncthreads();
    int wave = threadIdx.x >> 6, lane = threadIdx.x & 63;
    int n = blockIdx.x * 4 + wave;
    float qx = sx[n], qy = sy[n], qz = sz[n], qs = sq[n];
    float d[16];
    #pragma unroll
    for (int t = 0; t < 16; ++t) {
        int m = lane + 64*t;
        float dot = qx*sx[m] + qy*sy[m] + qz*sz[m];
        float d2 = qs + sq[m] - 2.f*dot;           // exact reference formula
        d[t] = fmaxf(d2, 0.f);                     // clamp like sqrt(max(d2,0))
    }
    int out_base = (b*NN + n) * KNBR;
    for (int it = 0; it < KNBR; ++it) {
        float bd = 3.4e38f; int bm = 1 << 30;
        #pragma unroll
        for (int t = 0; t < 16; ++t) {
            // strict < keeps the lowest t (lowest index) on ties
            if (d[t] < bd) { bd = d[t]; bm = lane + 64*t; }
        }
        #pragma unroll
        for (int off = 32; off >= 1; off >>= 1) {
            float od = __shfl_xor(bd, off);
            int   om = __shfl_xor(bm, off);
            if (od < bd || (od == bd && om < bm)) { bd = od; bm = om; }
        }
        if (lane == 0) idxout[out_base + it] = bm;
        // evict selected element; static indices only (avoid scratch)
        int sel = bm >> 6;
        int mine = ((bm & 63) == lane);
        #pragma unroll
        for (int t = 0; t < 16; ++t)
            if (mine && t == sel) d[t] = 3.4e38f;
    }
}

// ---------------- tiled f32 GEMM core: C[M,256] = A[M,256] @ W[256,256] ----------------
// tile 128x64, 256 threads, per-thread 8x4
template<int EPI>
__device__ __forceinline__ void gemm_core(
    const float* __restrict__ A, const float* __restrict__ W, float* __restrict__ C,
    const float* __restrict__ resid, const void* __restrict__ mask, int u8) {
    __shared__ float As[16][132];   // [k][m], rows 16B-aligned (132*4=528=33*16)
    __shared__ float Bs[16][68];    // [k][n], rows 16B-aligned (68*4=272=17*16)
    int bm = blockIdx.x * 128;
    int bn = blockIdx.y * 64;
    int tid = threadIdx.x;
    int tm = (tid & 15) * 8;
    int tn = (tid >> 4) * 4;
    float acc[8][4];
    #pragma unroll
    for (int i = 0; i < 8; ++i)
        #pragma unroll
        for (int j = 0; j < 4; ++j) acc[i][j] = 0.f;

    for (int k0 = 0; k0 < 256; k0 += 16) {
        // stage A tile: 128x16 = 512 float4 slots, coalesced
        #pragma unroll
        for (int l0 = 0; l0 < 2; ++l0) {
            int l = tid + l0*256;
            int r = l >> 2, c4 = (l & 3) * 4;
            float4 a4 = *(const float4*)(&A[(size_t)(bm + r)*256 + k0 + c4]);
            As[c4+0][r] = a4.x; As[c4+1][r] = a4.y;
            As[c4+2][r] = a4.z; As[c4+3][r] = a4.w;
        }
        { // stage B tile: 16x64 = 256 float4 slots, coalesced
            int kr = tid >> 4, c4 = (tid & 15) * 4;
            float4 b4 = *(const float4*)(&W[(size_t)(k0 + kr)*256 + bn + c4]);
            Bs[kr][c4+0] = b4.x; Bs[kr][c4+1] = b4.y;
            Bs[kr][c4+2] = b4.z; Bs[kr][c4+3] = b4.w;
        }
        __syncthreads();
        #pragma unroll
        for (int kk = 0; kk < 16; ++kk) {
            float4 a0 = *(const float4*)(&As[kk][tm]);
            float4 a1 = *(const float4*)(&As[kk][tm+4]);
            float4 bb = *(const float4*)(&Bs[kk][tn]);
            float a[8] = {a0.x,a0.y,a0.z,a0.w,a1.x,a1.y,a1.z,a1.w};
            float bv[4] = {bb.x,bb.y,bb.z,bb.w};
            #pragma unroll
            for (int i = 0; i < 8; ++i)
                #pragma unroll
                for (int j = 0; j < 4; ++j)
                    acc[i][j] += a[i]*bv[j];
        }
        __syncthreads();
    }
    #pragma unroll
    for (int i = 0; i < 8; ++i) {
        int row = bm + tm + i;
        float4 r4;
        if (EPI) {
            int valid = get_valid(mask, row, u8);
            const float4 x4 = *(const float4*)(&resid[(size_t)row*256 + bn + tn]);
            r4.x = valid ? x4.x + acc[i][0] : 0.f;
            r4.y = valid ? x4.y + acc[i][1] : 0.f;
            r4.z = valid ? x4.z + acc[i][2] : 0.f;
            r4.w = valid ? x4.w + acc[i][3] : 0.f;
        } else {
            r4 = make_float4(acc[i][0], acc[i][1], acc[i][2], acc[i][3]);
        }
        *(float4*)(&C[(size_t)row*256 + bn + tn]) = r4;
    }
}

__global__ __launch_bounds__(256) void gemm3_kernel(
    const float* __restrict__ xpe, const float* __restrict__ x,
    const float* __restrict__ Wq, const float* __restrict__ Wk, const float* __restrict__ Wv,
    float* __restrict__ q, float* __restrict__ k, float* __restrict__ v) {
    const float* A; const float* W; float* C;
    if (blockIdx.z == 0)      { A = xpe; W = Wq; C = q; }
    else if (blockIdx.z == 1) { A = xpe; W = Wk; C = k; }
    else                      { A = x;   W = Wv; C = v; }
    gemm_core<0>(A, W, C, nullptr, nullptr, 0);
}

__global__ __launch_bounds__(256) void gemm_out_kernel(
    const float* __restrict__ ao, const float* __restrict__ Wo,
    const float* __restrict__ x, const void* __restrict__ mask,
    const int* __restrict__ flag, float* __restrict__ out) {
    int u8 = *flag;
    gemm_core<1>(ao, Wo, out, x, mask, u8);
}

// ---------------- local attention: one wave per token ----------------
// lane = nbr*4 + sub; sub covers dh=32 in 8-elem quarters
__global__ __launch_bounds__(256) void attn_kernel(
    const float* __restrict__ q, const float* __restrict__ k, const float* __restrict__ v,
    const int* __restrict__ idx, const void* __restrict__ mask,
    const int* __restrict__ flag, float* __restrict__ ao) {
    int u8 = *flag;
    int wave = threadIdx.x >> 6, lane = threadIdx.x & 63;
    int t = blockIdx.x * 4 + wave;
    int b = t >> 10;
    int sub = lane & 3, nbr = lane >> 2;
    int j = idx[(size_t)t*KNBR + nbr];
    int nv = get_valid(mask, b*NN + j, u8);
    const float* qb = q + (size_t)t*DD;
    const float* kb = k + ((size_t)(b*NN + j))*DD;
    const float* vb = v + ((size_t)(b*NN + j))*DD;

    float s[8];
    #pragma unroll
    for (int h = 0; h < 8; ++h) {
        const float4* qp = (const float4*)(qb + h*32 + sub*8);
        const float4* kp = (const float4*)(kb + h*32 + sub*8);
        float4 q0 = qp[0], q1 = qp[1], k0 = kp[0], k1 = kp[1];
        float acc = q0.x*k0.x + q0.y*k0.y + q0.z*k0.z + q0.w*k0.w
                  + q1.x*k1.x + q1.y*k1.y + q1.z*k1.z + q1.w*k1.w;
        acc += __shfl_xor(acc, 1);
        acc += __shfl_xor(acc, 2);
        s[h] = acc * 0.17677669529663688f;   // 1/sqrt(32)
        if (!nv) s[h] = -1e9f;
    }
    float w[8];
    #pragma unroll
    for (int h = 0; h < 8; ++h) {
        float m = s[h];
        #pragma unroll
        for (int off = 4; off <= 32; off <<= 1) m = fmaxf(m, __shfl_xor(m, off));
        float e = expf(s[h] - m);
        float sum = e;
        #pragma unroll
        for (int off = 4; off <= 32; off <<= 1) sum += __shfl_xor(sum, off);
        w[h] = e / sum;
    }
    #pragma unroll
    for (int h = 0; h < 8; ++h) {
        const float4* vp = (const float4*)(vb + h*32 + sub*8);
        float4 v0 = vp[0], v1 = vp[1];
        float o[8] = {w[h]*v0.x, w[h]*v0.y, w[h]*v0.z, w[h]*v0.w,
                      w[h]*v1.x, w[h]*v1.y, w[h]*v1.z, w[h]*v1.w};
        #pragma unroll
        for (int e2 = 0; e2 < 8; ++e2) {
            #pragma unroll
            for (int off = 4; off <= 32; off <<= 1) o[e2] += __shfl_xor(o[e2], off);
        }
        if (nbr == 0) {
            float4* op = (float4*)(ao + (size_t)t*DD + h*32 + sub*8);
            op[0] = make_float4(o[0], o[1], o[2], o[3]);
            op[1] = make_float4(o[4], o[5], o[6], o[7]);
        }
    }
}

extern "C" void kernel_launch(void* const* d_in, const int* in_sizes, int n_in,
                              void* d_out, int out_size, void* d_ws, size_t ws_size,
                              hipStream_t stream) {
    const float* x    = (const float*)d_in[0];
    const float* xpos = (const float*)d_in[1];
    const void*  mask = d_in[2];
    const float* Wq   = (const float*)d_in[3];
    const float* Wk   = (const float*)d_in[4];
    const float* Wv   = (const float*)d_in[5];
    const float* Wo   = (const float*)d_in[6];
    float* out = (float*)d_out;
    char*  ws  = (char*)d_ws;
    if (ws_size < WS_NEED) return;   // cannot run without scratch

    int*   flag = (int*)  (ws + OFF_FLAG);
    float* xpe  = (float*)(ws + OFF_XPE);
    float* q    = (float*)(ws + OFF_Q);
    float* k    = (float*)(ws + OFF_K);
    float* v    = (float*)(ws + OFF_V);
    float* ao   = (float*)(ws + OFF_AO);
    int*   idx  = (int*)  (ws + OFF_IDX);

    detect_mask_kernel<<<1, 256, 0, stream>>>((const unsigned*)mask, flag);
    pe_xpe_kernel<<<MM, 256, 0, stream>>>(x, xpos, mask, flag, xpe);
    knn_kernel<<<dim3(NN/4, BB), 256, 0, stream>>>(xpos, idx);
    gemm3_kernel<<<dim3(MM/128, 4, 3), 256, 0, stream>>>(xpe, x, Wq, Wk, Wv, q, k, v);
    attn_kernel<<<MM/4, 256, 0, stream>>>(q, k, v, idx, mask, flag, ao);
    gemm_out_kernel<<<dim3(MM/128, 4), 256, 0, stream>>>(ao, Wo, x, mask, flag, out);
}

// Round 2
// 180.653 us; speedup vs baseline: 1.4698x; 1.4698x over previous
//
#include <hip/hip_runtime.h>
#include <math.h>

// Problem constants
#define BB 16
#define NN 1024
#define DD 256
#define HH 8
#define DHH 32
#define KNBR 16
#define MM (BB*NN)   // 16384 tokens

typedef __attribute__((ext_vector_type(8))) short  bf16x8;
typedef __attribute__((ext_vector_type(4))) float  f32x4;
typedef __attribute__((ext_vector_type(8))) unsigned short ushort8;

// ---------------- workspace layout (bytes) ----------------
#define OFF_FLAG 0
#define OFF_XPE  ((size_t)256)                          // bf16 x+pe  (8 MB) — aliased by aobf later
#define OFF_XBF  (OFF_XPE + (size_t)MM*DD*2)            // bf16 x     (8 MB)
#define OFF_WT   (OFF_XBF + (size_t)MM*DD*2)            // bf16 WT[4][256][256] (512 KB)
#define OFF_Q    (OFF_WT  + (size_t)4*DD*DD*2)          // f32 q (16 MB)
#define OFF_K    (OFF_Q   + (size_t)MM*DD*4)
#define OFF_V    (OFF_K   + (size_t)MM*DD*4)
#define OFF_AO   OFF_XPE                                // bf16 attn-out reuses xpe region
#define OFF_IDX  (OFF_V   + (size_t)MM*DD*4)
#define WS_NEED  (OFF_IDX + (size_t)MM*KNBR*4)

// ---------------- bf16 helpers ----------------
__device__ __forceinline__ float bf2f(unsigned short u) {
    unsigned x = ((unsigned)u) << 16;
    return __builtin_bit_cast(float, x);
}
__device__ __forceinline__ unsigned short f2bf(float f) {
    unsigned x = __builtin_bit_cast(unsigned, f);
    unsigned r = (x + 0x7fffu + ((x >> 16) & 1u)) >> 16;   // RNE
    return (unsigned short)r;
}

// ---------------- mask format detection ----------------
__global__ void detect_mask_kernel(const unsigned* __restrict__ mraw, int* __restrict__ flag) {
    __shared__ int s_u8, s_f32;
    if (threadIdx.x == 0) { s_u8 = 0; s_f32 = 0; }
    __syncthreads();
    int u8 = 0, f32 = 0;
    for (int i = threadIdx.x; i < 4096; i += 256) {
        unsigned w = mraw[i];
        if (w == 0x3f800000u) f32 = 1;
        else if (w > 1u) u8 = 1;
    }
    if (u8)  atomicOr(&s_u8, 1);
    if (f32) atomicOr(&s_f32, 1);
    __syncthreads();
    if (threadIdx.x == 0) *flag = (s_f32 ? 0 : (s_u8 ? 1 : 0));
}

__device__ __forceinline__ int get_valid(const void* m, int i, int u8) {
    if (u8) return ((const unsigned char*)m)[i] != 0;
    return ((const unsigned*)m)[i] != 0u;
}

// ---------------- weight convert + transpose: WT[w][n][k] = bf16(W[k][n]) ----------------
__global__ __launch_bounds__(256) void cvtW_kernel(
    const float* __restrict__ Wq, const float* __restrict__ Wk,
    const float* __restrict__ Wv, const float* __restrict__ Wo,
    unsigned short* __restrict__ WT) {
    int wsel = blockIdx.y;
    const float* W = (wsel == 0) ? Wq : (wsel == 1) ? Wk : (wsel == 2) ? Wv : Wo;
    int kk = blockIdx.x;           // 0..255
    int n  = threadIdx.x;          // 0..255
    WT[(size_t)wsel*65536 + (size_t)n*256 + kk] = f2bf(W[(size_t)kk*256 + n]);
}

// ---------------- PE + bf16 conversion of (x+pe) and x ----------------
__global__ __launch_bounds__(256) void pe_cvt_kernel(
    const float* __restrict__ x, const float* __restrict__ xpos,
    const void* __restrict__ mask, const int* __restrict__ flag,
    unsigned short* __restrict__ xpebf, unsigned short* __restrict__ xbf) {
    int t = blockIdx.x;
    int c = threadIdx.x;
    int u8 = *flag;
    int valid = get_valid(mask, t, u8);
    float pos = xpos[(size_t)t*3 + ((c < 128) ? 1 : 0)];
    int g = c & 127;
    int j = g >> 1;
    // 2*pi / 10000^(j/64) = 2*pi * 2^(-j * log2(10000)/64)
    float recip = 6.2831853071795864f * exp2f(-(float)j * 0.20762050593045952f);
    float th = pos * recip;
    float pe = (g & 1) ? cosf(th) : sinf(th);
    if (!valid) pe = 0.f;
    size_t o = (size_t)t*DD + c;
    float xv = x[o];
    xbf[o]   = f2bf(xv);
    xpebf[o] = f2bf(xv + pe);
}

// ---------------- KNN: one wave per query row (exact f32, unchanged) ----------------
__global__ __launch_bounds__(256) void knn_kernel(const float* __restrict__ xpos,
                                                  int* __restrict__ idxout) {
    __shared__ float sx[NN], sy[NN], sz[NN], sq[NN];
    int b = blockIdx.y;
    for (int i = threadIdx.x; i < NN; i += 256) {
        float px = xpos[((size_t)b*NN + i)*3 + 0];
        float py = xpos[((size_t)b*NN + i)*3 + 1];
        float pz = xpos[((size_t)b*NN + i)*3 + 2];
        sx[i] = px; sy[i] = py; sz[i] = pz;
        sq[i] = px*px + py*py + pz*pz;
    }
    __syncthreads();
    int wave = threadIdx.x >> 6, lane = threadIdx.x & 63;
    int n = blockIdx.x * 4 + wave;
    float qx = sx[n], qy = sy[n], qz = sz[n], qs = sq[n];
    float d[16];
    #pragma unroll
    for (int t = 0; t < 16; ++t) {
        int m = lane + 64*t;
        float dot = qx*sx[m] + qy*sy[m] + qz*sz[m];
        float d2 = qs + sq[m] - 2.f*dot;
        d[t] = fmaxf(d2, 0.f);
    }
    int out_base = (b*NN + n) * KNBR;
    for (int it = 0; it < KNBR; ++it) {
        float bd = 3.4e38f; int bm = 1 << 30;
        #pragma unroll
        for (int t = 0; t < 16; ++t) {
            if (d[t] < bd) { bd = d[t]; bm = lane + 64*t; }
        }
        #pragma unroll
        for (int off = 32; off >= 1; off >>= 1) {
            float od = __shfl_xor(bd, off);
            int   om = __shfl_xor(bm, off);
            if (od < bd || (od == bd && om < bm)) { bd = od; bm = om; }
        }
        if (lane == 0) idxout[out_base + it] = bm;
        int sel = bm >> 6;
        int mine = ((bm & 63) == lane);
        #pragma unroll
        for (int t = 0; t < 16; ++t)
            if (mine && t == sel) d[t] = 3.4e38f;
    }
}

// ---------------- bf16 MFMA GEMM: C[M,256] = A[M,256] @ W[256,256] ----------------
// A: bf16 [M][K] row-major; BT: bf16 [N][K] (W transposed); C: f32 [M][256].
// Tile 128x128, BK=32, 4 waves, each wave 64x64 = 4x4 fragments of 16x16x32.
template<int EPI>
__device__ __forceinline__ void gemm_mfma_core(
    const unsigned short* __restrict__ A, const unsigned short* __restrict__ BT,
    float* __restrict__ C, const float* __restrict__ resid,
    const void* __restrict__ mask, int u8) {
    __shared__ __align__(16) unsigned short As[128][32];
    __shared__ __align__(16) unsigned short Bs[128][32];
    int bm = blockIdx.x * 128;
    int bn = blockIdx.y * 128;
    int tid = threadIdx.x;
    int w = tid >> 6, l = tid & 63;
    int wr = w >> 1, wc = w & 1;

    f32x4 acc[4][4] = {};

    for (int kt = 0; kt < 8; ++kt) {
        // stage A tile 128x32 bf16 = 8192 B: 512 x 16B chunks; wave-chunk = 1024 B
        #pragma unroll
        for (int j = 0; j < 2; ++j) {
            int c  = (w + j*4)*64 + l;        // 0..511
            int row = c >> 2;                 // 0..127
            int cb  = (c & 3) * 16;           // byte col within 64B row
            const char* ga = (const char*)A + ((size_t)(bm + row)*256 + kt*32)*2 + cb;
            char* la = (char*)&As[0][0] + (size_t)(w + j*4)*1024;   // wave-uniform dest
            __builtin_amdgcn_global_load_lds(
                (const __attribute__((address_space(1))) unsigned*)ga,
                (__attribute__((address_space(3))) unsigned*)la, 16, 0, 0);
            const char* gb = (const char*)BT + ((size_t)(bn + row)*256 + kt*32)*2 + cb;
            char* lb = (char*)&Bs[0][0] + (size_t)(w + j*4)*1024;
            __builtin_amdgcn_global_load_lds(
                (const __attribute__((address_space(1))) unsigned*)gb,
                (__attribute__((address_space(3))) unsigned*)lb, 16, 0, 0);
        }
        __syncthreads();   // compiler drains vmcnt before s_barrier

        bf16x8 af[4], bfr[4];
        #pragma unroll
        for (int m = 0; m < 4; ++m)
            af[m] = *(const bf16x8*)&As[wr*64 + m*16 + (l & 15)][(l >> 4) * 8];
        #pragma unroll
        for (int n = 0; n < 4; ++n)
            bfr[n] = *(const bf16x8*)&Bs[wc*64 + n*16 + (l & 15)][(l >> 4) * 8];
        #pragma unroll
        for (int m = 0; m < 4; ++m)
            #pragma unroll
            for (int n = 0; n < 4; ++n)
                acc[m][n] = __builtin_amdgcn_mfma_f32_16x16x32_bf16(af[m], bfr[n], acc[m][n], 0, 0, 0);
        __syncthreads();
    }

    // epilogue: C/D layout col = lane&15, row = (lane>>4)*4 + r  [m89-verified]
    int colb = bn + wc*64 + (l & 15);
    #pragma unroll
    for (int m = 0; m < 4; ++m) {
        int row0 = bm + wr*64 + m*16 + (l >> 4)*4;
        #pragma unroll
        for (int r = 0; r < 4; ++r) {
            int row = row0 + r;
            int valid = 1;
            if (EPI) valid = get_valid(mask, row, u8);
            #pragma unroll
            for (int n = 0; n < 4; ++n) {
                int cc = colb + n*16;
                float val = acc[m][n][r];
                if (EPI) {
                    val = valid ? resid[(size_t)row*256 + cc] + val : 0.f;
                }
                C[(size_t)row*256 + cc] = val;
            }
        }
    }
}

__global__ __launch_bounds__(256) void gemm_qkv_mfma(
    const unsigned short* __restrict__ xpebf, const unsigned short* __restrict__ xbf,
    const unsigned short* __restrict__ WT,
    float* __restrict__ q, float* __restrict__ k, float* __restrict__ v) {
    int z = blockIdx.z;
    const unsigned short* A  = (z == 2) ? xbf : xpebf;
    const unsigned short* BT = WT + (size_t)z * 65536;
    float* C = (z == 0) ? q : (z == 1) ? k : v;
    gemm_mfma_core<0>(A, BT, C, nullptr, nullptr, 0);
}

__global__ __launch_bounds__(256) void gemm_out_mfma(
    const unsigned short* __restrict__ aobf, const unsigned short* __restrict__ WT,
    const float* __restrict__ x, const void* __restrict__ mask,
    const int* __restrict__ flag, float* __restrict__ out) {
    int u8 = *flag;
    gemm_mfma_core<1>(aobf, WT + (size_t)3 * 65536, out, x, mask, u8);
}

// ---------------- local attention: one wave per token (f32 q/k/v, bf16 out) ----------------
__global__ __launch_bounds__(256) void attn_kernel(
    const float* __restrict__ q, const float* __restrict__ k, const float* __restrict__ v,
    const int* __restrict__ idx, const void* __restrict__ mask,
    const int* __restrict__ flag, unsigned short* __restrict__ aobf) {
    int u8 = *flag;
    int wave = threadIdx.x >> 6, lane = threadIdx.x & 63;
    int t = blockIdx.x * 4 + wave;
    int b = t >> 10;
    int sub = lane & 3, nbr = lane >> 2;
    int j = idx[(size_t)t*KNBR + nbr];
    int nv = get_valid(mask, b*NN + j, u8);
    const float* qb = q + (size_t)t*DD;
    const float* kb = k + ((size_t)(b*NN + j))*DD;
    const float* vb = v + ((size_t)(b*NN + j))*DD;

    float s[8];
    #pragma unroll
    for (int h = 0; h < 8; ++h) {
        const float4* qp = (const float4*)(qb + h*32 + sub*8);
        const float4* kp = (const float4*)(kb + h*32 + sub*8);
        float4 q0 = qp[0], q1 = qp[1], k0 = kp[0], k1 = kp[1];
        float acc = q0.x*k0.x + q0.y*k0.y + q0.z*k0.z + q0.w*k0.w
                  + q1.x*k1.x + q1.y*k1.y + q1.z*k1.z + q1.w*k1.w;
        acc += __shfl_xor(acc, 1);
        acc += __shfl_xor(acc, 2);
        s[h] = acc * 0.17677669529663688f;   // 1/sqrt(32)
        if (!nv) s[h] = -1e9f;
    }
    float w[8];
    #pragma unroll
    for (int h = 0; h < 8; ++h) {
        float m = s[h];
        #pragma unroll
        for (int off = 4; off <= 32; off <<= 1) m = fmaxf(m, __shfl_xor(m, off));
        float e = expf(s[h] - m);
        float sum = e;
        #pragma unroll
        for (int off = 4; off <= 32; off <<= 1) sum += __shfl_xor(sum, off);
        w[h] = e / sum;
    }
    #pragma unroll
    for (int h = 0; h < 8; ++h) {
        const float4* vp = (const float4*)(vb + h*32 + sub*8);
        float4 v0 = vp[0], v1 = vp[1];
        float o[8] = {w[h]*v0.x, w[h]*v0.y, w[h]*v0.z, w[h]*v0.w,
                      w[h]*v1.x, w[h]*v1.y, w[h]*v1.z, w[h]*v1.w};
        #pragma unroll
        for (int e2 = 0; e2 < 8; ++e2) {
            #pragma unroll
            for (int off = 4; off <= 32; off <<= 1) o[e2] += __shfl_xor(o[e2], off);
        }
        if (nbr == 0) {
            ushort8 st;
            #pragma unroll
            for (int e2 = 0; e2 < 8; ++e2) st[e2] = f2bf(o[e2]);
            *(ushort8*)(aobf + (size_t)t*DD + h*32 + sub*8) = st;
        }
    }
}

extern "C" void kernel_launch(void* const* d_in, const int* in_sizes, int n_in,
                              void* d_out, int out_size, void* d_ws, size_t ws_size,
                              hipStream_t stream) {
    const float* x    = (const float*)d_in[0];
    const float* xpos = (const float*)d_in[1];
    const void*  mask = d_in[2];
    const float* Wq   = (const float*)d_in[3];
    const float* Wk   = (const float*)d_in[4];
    const float* Wv   = (const float*)d_in[5];
    const float* Wo   = (const float*)d_in[6];
    float* out = (float*)d_out;
    char*  ws  = (char*)d_ws;
    if (ws_size < WS_NEED) return;

    int*            flag  = (int*)           (ws + OFF_FLAG);
    unsigned short* xpebf = (unsigned short*)(ws + OFF_XPE);
    unsigned short* xbf   = (unsigned short*)(ws + OFF_XBF);
    unsigned short* WT    = (unsigned short*)(ws + OFF_WT);
    float*          q     = (float*)         (ws + OFF_Q);
    float*          k     = (float*)         (ws + OFF_K);
    float*          v     = (float*)         (ws + OFF_V);
    unsigned short* aobf  = (unsigned short*)(ws + OFF_AO);
    int*            idx   = (int*)           (ws + OFF_IDX);

    detect_mask_kernel<<<1, 256, 0, stream>>>((const unsigned*)mask, flag);
    cvtW_kernel<<<dim3(256, 4), 256, 0, stream>>>(Wq, Wk, Wv, Wo, WT);
    pe_cvt_kernel<<<MM, 256, 0, stream>>>(x, xpos, mask, flag, xpebf, xbf);
    knn_kernel<<<dim3(NN/4, BB), 256, 0, stream>>>(xpos, idx);
    gemm_qkv_mfma<<<dim3(MM/128, 2, 3), 256, 0, stream>>>(xpebf, xbf, WT, q, k, v);
    attn_kernel<<<MM/4, 256, 0, stream>>>(q, k, v, idx, mask, flag, aobf);
    gemm_out_mfma<<<dim3(MM/128, 2), 256, 0, stream>>>(aobf, WT, x, mask, flag, out);
}

// Round 3
// 132.709 us; speedup vs baseline: 2.0008x; 1.3613x over previous
//
#include <hip/hip_runtime.h>
#include <math.h>

// Problem constants
#define BB 16
#define NN 1024
#define DD 256
#define HH 8
#define DHH 32
#define KNBR 16
#define MM (BB*NN)   // 16384 tokens

typedef __attribute__((ext_vector_type(8))) short  bf16x8;
typedef __attribute__((ext_vector_type(4))) float  f32x4;
typedef __attribute__((ext_vector_type(2))) unsigned short u16x2;
typedef __attribute__((ext_vector_type(4))) unsigned short u16x4;

// ---------------- workspace layout (bytes) ----------------
#define OFF_FLAG 0
#define OFF_XPE  ((size_t)256)                          // bf16 x+pe (8 MB) — aliased by aobf later
#define OFF_XBF  (OFF_XPE + (size_t)MM*DD*2)            // bf16 x    (8 MB)
#define OFF_WT   (OFF_XBF + (size_t)MM*DD*2)            // bf16 WT[4][256][256] (512 KB)
#define OFF_Q    (OFF_WT  + (size_t)4*DD*DD*2)          // bf16 q (8 MB)
#define OFF_K    (OFF_Q   + (size_t)MM*DD*2)
#define OFF_V    (OFF_K   + (size_t)MM*DD*2)
#define OFF_AO   OFF_XPE                                // bf16 attn-out reuses xpe region
#define OFF_IDX  (OFF_V   + (size_t)MM*DD*2)
#define WS_NEED  (OFF_IDX + (size_t)MM*KNBR*4)

// ---------------- bf16 helpers ----------------
__device__ __forceinline__ float bf2f(unsigned short u) {
    unsigned x = ((unsigned)u) << 16;
    return __builtin_bit_cast(float, x);
}
__device__ __forceinline__ unsigned short f2bf(float f) {
    unsigned x = __builtin_bit_cast(unsigned, f);
    unsigned r = (x + 0x7fffu + ((x >> 16) & 1u)) >> 16;   // RNE
    return (unsigned short)r;
}

// ---------------- mask format detection ----------------
__global__ void detect_mask_kernel(const unsigned* __restrict__ mraw, int* __restrict__ flag) {
    __shared__ int s_u8, s_f32;
    if (threadIdx.x == 0) { s_u8 = 0; s_f32 = 0; }
    __syncthreads();
    int u8 = 0, f32 = 0;
    for (int i = threadIdx.x; i < 4096; i += 256) {
        unsigned w = mraw[i];
        if (w == 0x3f800000u) f32 = 1;
        else if (w > 1u) u8 = 1;
    }
    if (u8)  atomicOr(&s_u8, 1);
    if (f32) atomicOr(&s_f32, 1);
    __syncthreads();
    if (threadIdx.x == 0) *flag = (s_f32 ? 0 : (s_u8 ? 1 : 0));
}

__device__ __forceinline__ int get_valid(const void* m, int i, int u8) {
    if (u8) return ((const unsigned char*)m)[i] != 0;
    return ((const unsigned*)m)[i] != 0u;
}

// ---------------- weight convert + transpose: WT[w][n][k] = bf16(W[k][n]) ----------------
__global__ __launch_bounds__(256) void cvtW_kernel(
    const float* __restrict__ Wq, const float* __restrict__ Wk,
    const float* __restrict__ Wv, const float* __restrict__ Wo,
    unsigned short* __restrict__ WT) {
    int wsel = blockIdx.y;
    const float* W = (wsel == 0) ? Wq : (wsel == 1) ? Wk : (wsel == 2) ? Wv : Wo;
    int kk = blockIdx.x;           // 0..255
    int n  = threadIdx.x;          // 0..255
    WT[(size_t)wsel*65536 + (size_t)n*256 + kk] = f2bf(W[(size_t)kk*256 + n]);
}

// ---------------- PE + bf16 conversion of (x+pe) and x ----------------
// Channel pair (2j, 2j+1) within each half shares theta: one sincos per pair.
__global__ __launch_bounds__(256) void pe_cvt_kernel(
    const float* __restrict__ x, const float* __restrict__ xpos,
    const void* __restrict__ mask, const int* __restrict__ flag,
    unsigned short* __restrict__ xpebf, unsigned short* __restrict__ xbf) {
    int tid = threadIdx.x;
    int t = blockIdx.x * 2 + (tid >> 7);
    int p = tid & 127;
    int u8 = *flag;
    int valid = get_valid(mask, t, u8);
    int half = p >> 6;             // 0 -> y channels [0,128), 1 -> x channels [128,256)
    int j = p & 63;
    float pos = xpos[(size_t)t*3 + (half ? 0 : 1)];
    // 2*pi / 10000^(j/64) = 2*pi * 2^(-j * log2(10000)/64)
    float recip = 6.2831853071795864f * exp2f(-(float)j * 0.20762050593045952f);
    float th = pos * recip;
    float s, c;
    __sincosf(th, &s, &c);
    if (!valid) { s = 0.f; c = 0.f; }
    size_t o = (size_t)t*DD + half*128 + 2*j;
    float2 xv = *(const float2*)(x + o);
    u16x2 xb; xb[0] = f2bf(xv.x);     xb[1] = f2bf(xv.y);
    u16x2 xp; xp[0] = f2bf(xv.x + s); xp[1] = f2bf(xv.y + c);
    *(u16x2*)(xbf + o)   = xb;
    *(u16x2*)(xpebf + o) = xp;
}

// ---------------- KNN: one wave per query row (exact f32, unchanged) ----------------
__global__ __launch_bounds__(256) void knn_kernel(const float* __restrict__ xpos,
                                                  int* __restrict__ idxout) {
    __shared__ float sx[NN], sy[NN], sz[NN], sq[NN];
    int b = blockIdx.y;
    for (int i = threadIdx.x; i < NN; i += 256) {
        float px = xpos[((size_t)b*NN + i)*3 + 0];
        float py = xpos[((size_t)b*NN + i)*3 + 1];
        float pz = xpos[((size_t)b*NN + i)*3 + 2];
        sx[i] = px; sy[i] = py; sz[i] = pz;
        sq[i] = px*px + py*py + pz*pz;
    }
    __syncthreads();
    int wave = threadIdx.x >> 6, lane = threadIdx.x & 63;
    int n = blockIdx.x * 4 + wave;
    float qx = sx[n], qy = sy[n], qz = sz[n], qs = sq[n];
    float d[16];
    #pragma unroll
    for (int t = 0; t < 16; ++t) {
        int m = lane + 64*t;
        float dot = qx*sx[m] + qy*sy[m] + qz*sz[m];
        float d2 = qs + sq[m] - 2.f*dot;
        d[t] = fmaxf(d2, 0.f);
    }
    int out_base = (b*NN + n) * KNBR;
    for (int it = 0; it < KNBR; ++it) {
        float bd = 3.4e38f; int bm = 1 << 30;
        #pragma unroll
        for (int t = 0; t < 16; ++t) {
            if (d[t] < bd) { bd = d[t]; bm = lane + 64*t; }
        }
        #pragma unroll
        for (int off = 32; off >= 1; off >>= 1) {
            float od = __shfl_xor(bd, off);
            int   om = __shfl_xor(bm, off);
            if (od < bd || (od == bd && om < bm)) { bd = od; bm = om; }
        }
        if (lane == 0) idxout[out_base + it] = bm;
        int sel = bm >> 6;
        int mine = ((bm & 63) == lane);
        #pragma unroll
        for (int t = 0; t < 16; ++t)
            if (mine && t == sel) d[t] = 3.4e38f;
    }
}

// ---------------- bf16 MFMA GEMM: C[M,256] = A[M,256] @ W[256,256] ----------------
// A: bf16 [M][K]; BT: bf16 [N][K]; C: bf16 (EPI=0) or f32 + residual + mask (EPI=1).
// Tile 128x128, BK=32, 4 waves, each wave 64x64 = 4x4 fragments of 16x16x32.
template<int EPI>
__device__ __forceinline__ void gemm_mfma_core(
    const unsigned short* __restrict__ A, const unsigned short* __restrict__ BT,
    void* __restrict__ C, const float* __restrict__ resid,
    const void* __restrict__ mask, int u8) {
    __shared__ __align__(16) unsigned short As[128][32];
    __shared__ __align__(16) unsigned short Bs[128][32];
    int bm = blockIdx.x * 128;
    int bn = blockIdx.y * 128;
    int tid = threadIdx.x;
    int w = tid >> 6, l = tid & 63;
    int wr = w >> 1, wc = w & 1;

    f32x4 acc[4][4] = {};

    for (int kt = 0; kt < 8; ++kt) {
        #pragma unroll
        for (int j = 0; j < 2; ++j) {
            int c  = (w + j*4)*64 + l;        // 0..511
            int row = c >> 2;                 // 0..127
            int cb  = (c & 3) * 16;           // byte col within 64B row
            const char* ga = (const char*)A + ((size_t)(bm + row)*256 + kt*32)*2 + cb;
            char* la = (char*)&As[0][0] + (size_t)(w + j*4)*1024;   // wave-uniform dest
            __builtin_amdgcn_global_load_lds(
                (const __attribute__((address_space(1))) unsigned*)ga,
                (__attribute__((address_space(3))) unsigned*)la, 16, 0, 0);
            const char* gb = (const char*)BT + ((size_t)(bn + row)*256 + kt*32)*2 + cb;
            char* lb = (char*)&Bs[0][0] + (size_t)(w + j*4)*1024;
            __builtin_amdgcn_global_load_lds(
                (const __attribute__((address_space(1))) unsigned*)gb,
                (__attribute__((address_space(3))) unsigned*)lb, 16, 0, 0);
        }
        __syncthreads();

        bf16x8 af[4], bfr[4];
        #pragma unroll
        for (int m = 0; m < 4; ++m)
            af[m] = *(const bf16x8*)&As[wr*64 + m*16 + (l & 15)][(l >> 4) * 8];
        #pragma unroll
        for (int n = 0; n < 4; ++n)
            bfr[n] = *(const bf16x8*)&Bs[wc*64 + n*16 + (l & 15)][(l >> 4) * 8];
        #pragma unroll
        for (int m = 0; m < 4; ++m)
            #pragma unroll
            for (int n = 0; n < 4; ++n)
                acc[m][n] = __builtin_amdgcn_mfma_f32_16x16x32_bf16(af[m], bfr[n], acc[m][n], 0, 0, 0);
        __syncthreads();
    }

    // epilogue: C/D layout col = lane&15, row = (lane>>4)*4 + r  [m89-verified]
    int colb = bn + wc*64 + (l & 15);
    #pragma unroll
    for (int m = 0; m < 4; ++m) {
        int row0 = bm + wr*64 + m*16 + (l >> 4)*4;
        #pragma unroll
        for (int r = 0; r < 4; ++r) {
            int row = row0 + r;
            int valid = 1;
            if (EPI) valid = get_valid(mask, row, u8);
            #pragma unroll
            for (int n = 0; n < 4; ++n) {
                int cc = colb + n*16;
                float val = acc[m][n][r];
                if (EPI) {
                    val = valid ? resid[(size_t)row*256 + cc] + val : 0.f;
                    ((float*)C)[(size_t)row*256 + cc] = val;
                } else {
                    ((unsigned short*)C)[(size_t)row*256 + cc] = f2bf(val);
                }
            }
        }
    }
}

__global__ __launch_bounds__(256) void gemm_qkv_mfma(
    const unsigned short* __restrict__ xpebf, const unsigned short* __restrict__ xbf,
    const unsigned short* __restrict__ WT,
    unsigned short* __restrict__ q, unsigned short* __restrict__ k,
    unsigned short* __restrict__ v) {
    int z = blockIdx.z;
    const unsigned short* A  = (z == 2) ? xbf : xpebf;
    const unsigned short* BT = WT + (size_t)z * 65536;
    unsigned short* C = (z == 0) ? q : (z == 1) ? k : v;
    gemm_mfma_core<0>(A, BT, C, nullptr, nullptr, 0);
}

__global__ __launch_bounds__(256) void gemm_out_mfma(
    const unsigned short* __restrict__ aobf, const unsigned short* __restrict__ WT,
    const float* __restrict__ x, const void* __restrict__ mask,
    const int* __restrict__ flag, float* __restrict__ out) {
    int u8 = *flag;
    gemm_mfma_core<1>(aobf, WT + (size_t)3 * 65536, out, x, mask, u8);
}

// ---------------- local attention: one wave per token, bf16 q/k/v ----------------
// Phase 1 (scores+softmax): lane = nbr*4 + sub (sub covers dh=32 in 8-elem quarters)
// Phase 2 (PV): lane owns 4 output channels; weights/indices via LDS broadcast.
__global__ __launch_bounds__(256) void attn_kernel(
    const unsigned short* __restrict__ q, const unsigned short* __restrict__ k,
    const unsigned short* __restrict__ v, const int* __restrict__ idx,
    const void* __restrict__ mask, const int* __restrict__ flag,
    unsigned short* __restrict__ aobf) {
    __shared__ int   s_j[4][16];
    __shared__ float s_w[4][16][8];
    int u8 = *flag;
    int wave = threadIdx.x >> 6, lane = threadIdx.x & 63;
    // XCD-chunked swizzle: 4096 blocks -> 512 consecutive blocks per XCD
    // (2 batches' bf16 k+v = 2 MB fits one XCD's 4 MB L2)
    int cpx = gridDim.x >> 3;
    int sb = ((int)blockIdx.x & 7) * cpx + ((int)blockIdx.x >> 3);
    int t = sb * 4 + wave;
    int b = t >> 10;
    int sub = lane & 3, nbr = lane >> 2;
    int j = idx[(size_t)t*KNBR + nbr];
    if (lane < 16) s_j[wave][lane] = idx[(size_t)t*KNBR + lane];
    int nv = get_valid(mask, b*NN + j, u8);
    const unsigned short* qb = q + (size_t)t*DD;
    const unsigned short* kb = k + ((size_t)(b*NN + j))*DD;

    float w[8];
    #pragma unroll
    for (int h = 0; h < 8; ++h) {
        bf16x8 qv = *(const bf16x8*)(qb + h*32 + sub*8);
        bf16x8 kv = *(const bf16x8*)(kb + h*32 + sub*8);
        float acc = 0.f;
        #pragma unroll
        for (int e = 0; e < 8; ++e)
            acc += bf2f((unsigned short)qv[e]) * bf2f((unsigned short)kv[e]);
        acc += __shfl_xor(acc, 1);
        acc += __shfl_xor(acc, 2);
        float s = nv ? acc * 0.17677669529663688f : -1e9f;   // 1/sqrt(32)
        float m = s;
        #pragma unroll
        for (int off = 4; off <= 32; off <<= 1) m = fmaxf(m, __shfl_xor(m, off));
        float e = __expf(s - m);
        float sum = e;
        #pragma unroll
        for (int off = 4; off <= 32; off <<= 1) sum += __shfl_xor(sum, off);
        w[h] = e / sum;
    }
    if (sub == 0) {
        #pragma unroll
        for (int h = 0; h < 8; ++h) s_w[wave][nbr][h] = w[h];
    }
    __syncthreads();

    // PV: channel c0 = lane*4 .. +3, head h = lane>>3
    int c0 = lane * 4;
    int h = lane >> 3;
    float o0 = 0.f, o1 = 0.f, o2 = 0.f, o3 = 0.f;
    #pragma unroll
    for (int kk = 0; kk < 16; ++kk) {
        int jj = s_j[wave][kk];
        float wk = s_w[wave][kk][h];
        u16x4 vv = *(const u16x4*)(v + ((size_t)(b*NN + jj))*DD + c0);
        o0 += wk * bf2f(vv[0]);
        o1 += wk * bf2f(vv[1]);
        o2 += wk * bf2f(vv[2]);
        o3 += wk * bf2f(vv[3]);
    }
    u16x4 st;
    st[0] = f2bf(o0); st[1] = f2bf(o1); st[2] = f2bf(o2); st[3] = f2bf(o3);
    *(u16x4*)(aobf + (size_t)t*DD + c0) = st;
}

extern "C" void kernel_launch(void* const* d_in, const int* in_sizes, int n_in,
                              void* d_out, int out_size, void* d_ws, size_t ws_size,
                              hipStream_t stream) {
    const float* x    = (const float*)d_in[0];
    const float* xpos = (const float*)d_in[1];
    const void*  mask = d_in[2];
    const float* Wq   = (const float*)d_in[3];
    const float* Wk   = (const float*)d_in[4];
    const float* Wv   = (const float*)d_in[5];
    const float* Wo   = (const float*)d_in[6];
    float* out = (float*)d_out;
    char*  ws  = (char*)d_ws;
    if (ws_size < WS_NEED) return;

    int*            flag  = (int*)           (ws + OFF_FLAG);
    unsigned short* xpebf = (unsigned short*)(ws + OFF_XPE);
    unsigned short* xbf   = (unsigned short*)(ws + OFF_XBF);
    unsigned short* WT    = (unsigned short*)(ws + OFF_WT);
    unsigned short* q     = (unsigned short*)(ws + OFF_Q);
    unsigned short* k     = (unsigned short*)(ws + OFF_K);
    unsigned short* v     = (unsigned short*)(ws + OFF_V);
    unsigned short* aobf  = (unsigned short*)(ws + OFF_AO);
    int*            idx   = (int*)           (ws + OFF_IDX);

    detect_mask_kernel<<<1, 256, 0, stream>>>((const unsigned*)mask, flag);
    cvtW_kernel<<<dim3(256, 4), 256, 0, stream>>>(Wq, Wk, Wv, Wo, WT);
    pe_cvt_kernel<<<MM/2, 256, 0, stream>>>(x, xpos, mask, flag, xpebf, xbf);
    knn_kernel<<<dim3(NN/4, BB), 256, 0, stream>>>(xpos, idx);
    gemm_qkv_mfma<<<dim3(MM/128, 2, 3), 256, 0, stream>>>(xpebf, xbf, WT, q, k, v);
    attn_kernel<<<MM/4, 256, 0, stream>>>(q, k, v, idx, mask, flag, aobf);
    gemm_out_mfma<<<dim3(MM/128, 2), 256, 0, stream>>>(aobf, WT, x, mask, flag, out);
}

// Round 4
// 127.493 us; speedup vs baseline: 2.0827x; 1.0409x over previous
//
#include <hip/hip_runtime.h>
#include <math.h>

// Problem constants
#define BB 16
#define NN 1024
#define DD 256
#define HH 8
#define DHH 32
#define KNBR 16
#define MM (BB*NN)   // 16384 tokens

typedef __attribute__((ext_vector_type(8))) short  bf16x8;
typedef __attribute__((ext_vector_type(4))) float  f32x4;
typedef __attribute__((ext_vector_type(2))) unsigned short u16x2;
typedef __attribute__((ext_vector_type(4))) unsigned short u16x4;

// ---------------- workspace layout (bytes) ----------------
#define OFF_FLAG 0
#define OFF_XPE  ((size_t)256)                          // bf16 x+pe (8 MB) — aliased by aobf later
#define OFF_XBF  (OFF_XPE + (size_t)MM*DD*2)            // bf16 x    (8 MB)
#define OFF_WT   (OFF_XBF + (size_t)MM*DD*2)            // bf16 WT[4][256][256] (512 KB)
#define OFF_Q    (OFF_WT  + (size_t)4*DD*DD*2)          // bf16 q (8 MB)
#define OFF_K    (OFF_Q   + (size_t)MM*DD*2)
#define OFF_V    (OFF_K   + (size_t)MM*DD*2)
#define OFF_AO   OFF_XPE                                // bf16 attn-out reuses xpe region
#define OFF_IDX  (OFF_V   + (size_t)MM*DD*2)
#define WS_NEED  (OFF_IDX + (size_t)MM*KNBR*4)

// ---------------- bf16 helpers ----------------
__device__ __forceinline__ float bf2f(unsigned short u) {
    unsigned x = ((unsigned)u) << 16;
    return __builtin_bit_cast(float, x);
}
__device__ __forceinline__ unsigned short f2bf(float f) {
    unsigned x = __builtin_bit_cast(unsigned, f);
    unsigned r = (x + 0x7fffu + ((x >> 16) & 1u)) >> 16;   // RNE
    return (unsigned short)r;
}
__device__ __forceinline__ int mbcnt64(unsigned long long b) {
    // popcount of b restricted to lanes strictly below this lane
    return __builtin_amdgcn_mbcnt_hi((unsigned)(b >> 32),
           __builtin_amdgcn_mbcnt_lo((unsigned)b, 0));
}

__device__ __forceinline__ int get_valid(const void* m, int i, int u8) {
    if (u8) return ((const unsigned char*)m)[i] != 0;
    return ((const unsigned*)m)[i] != 0u;
}

// ---------------- fused: mask detect (block 0) + weight cvt/transpose ----------------
// flag: 0 = 4-byte elements (int32/float32), 1 = 1-byte (uint8 bool)
__global__ __launch_bounds__(256) void detect_cvtw_kernel(
    const unsigned* __restrict__ mraw, int* __restrict__ flag,
    const float* __restrict__ Wq, const float* __restrict__ Wk,
    const float* __restrict__ Wv, const float* __restrict__ Wo,
    unsigned short* __restrict__ WT) {
    int bid = blockIdx.x;
    if (bid == 0) {
        __shared__ int s_u8, s_f32;
        if (threadIdx.x == 0) { s_u8 = 0; s_f32 = 0; }
        __syncthreads();
        int u8 = 0, f32 = 0;
        for (int i = threadIdx.x; i < 4096; i += 256) {
            unsigned w = mraw[i];
            if (w == 0x3f800000u) f32 = 1;
            else if (w > 1u) u8 = 1;
        }
        if (u8)  atomicOr(&s_u8, 1);
        if (f32) atomicOr(&s_f32, 1);
        __syncthreads();
        if (threadIdx.x == 0) *flag = (s_f32 ? 0 : (s_u8 ? 1 : 0));
    } else {
        int g = bid - 1;                 // 0..1023
        int wsel = g >> 8;               // 0..3
        int kk = g & 255;                // 0..255
        const float* W = (wsel == 0) ? Wq : (wsel == 1) ? Wk : (wsel == 2) ? Wv : Wo;
        int n = threadIdx.x;
        WT[(size_t)wsel*65536 + (size_t)n*256 + kk] = f2bf(W[(size_t)kk*256 + n]);
    }
}

// ---------------- PE + bf16 conversion of (x+pe) and x ----------------
__global__ __launch_bounds__(256) void pe_cvt_kernel(
    const float* __restrict__ x, const float* __restrict__ xpos,
    const void* __restrict__ mask, const int* __restrict__ flag,
    unsigned short* __restrict__ xpebf, unsigned short* __restrict__ xbf) {
    int tid = threadIdx.x;
    int t = blockIdx.x * 2 + (tid >> 7);
    int p = tid & 127;
    int u8 = *flag;
    int valid = get_valid(mask, t, u8);
    int half = p >> 6;             // 0 -> y channels [0,128), 1 -> x channels [128,256)
    int j = p & 63;
    float pos = xpos[(size_t)t*3 + (half ? 0 : 1)];
    float recip = 6.2831853071795864f * exp2f(-(float)j * 0.20762050593045952f);
    float th = pos * recip;
    float s, c;
    __sincosf(th, &s, &c);
    if (!valid) { s = 0.f; c = 0.f; }
    size_t o = (size_t)t*DD + half*128 + 2*j;
    float2 xv = *(const float2*)(x + o);
    u16x2 xb; xb[0] = f2bf(xv.x);     xb[1] = f2bf(xv.y);
    u16x2 xp; xp[0] = f2bf(xv.x + s); xp[1] = f2bf(xv.y + c);
    *(u16x2*)(xbf + o)   = xb;
    *(u16x2*)(xpebf + o) = xp;
}

// ---------------- bf16 MFMA GEMM core: C[M,256] = A[M,256] @ W[256,256] ----------------
// Tile 128x128, BK=32, 4 waves, each wave 64x64 = 4x4 fragments of 16x16x32.
template<int EPI>
__device__ __forceinline__ void gemm_mfma_core(
    const unsigned short* __restrict__ A, const unsigned short* __restrict__ BT,
    void* __restrict__ C, const float* __restrict__ resid,
    const void* __restrict__ mask, int u8, int bm, int bn, char* smem) {
    unsigned short (*As)[32] = (unsigned short (*)[32])smem;
    unsigned short (*Bs)[32] = (unsigned short (*)[32])(smem + 8192);
    int tid = threadIdx.x;
    int w = tid >> 6, l = tid & 63;
    int wr = w >> 1, wc = w & 1;

    f32x4 acc[4][4] = {};

    for (int kt = 0; kt < 8; ++kt) {
        #pragma unroll
        for (int j = 0; j < 2; ++j) {
            int c  = (w + j*4)*64 + l;        // 0..511
            int row = c >> 2;                 // 0..127
            int cb  = (c & 3) * 16;           // byte col within 64B row
            const char* ga = (const char*)A + ((size_t)(bm + row)*256 + kt*32)*2 + cb;
            char* la = (char*)As + (size_t)(w + j*4)*1024;   // wave-uniform dest
            __builtin_amdgcn_global_load_lds(
                (const __attribute__((address_space(1))) unsigned*)ga,
                (__attribute__((address_space(3))) unsigned*)la, 16, 0, 0);
            const char* gb = (const char*)BT + ((size_t)(bn + row)*256 + kt*32)*2 + cb;
            char* lb = (char*)Bs + (size_t)(w + j*4)*1024;
            __builtin_amdgcn_global_load_lds(
                (const __attribute__((address_space(1))) unsigned*)gb,
                (__attribute__((address_space(3))) unsigned*)lb, 16, 0, 0);
        }
        __syncthreads();

        bf16x8 af[4], bfr[4];
        #pragma unroll
        for (int m = 0; m < 4; ++m)
            af[m] = *(const bf16x8*)&As[wr*64 + m*16 + (l & 15)][(l >> 4) * 8];
        #pragma unroll
        for (int n = 0; n < 4; ++n)
            bfr[n] = *(const bf16x8*)&Bs[wc*64 + n*16 + (l & 15)][(l >> 4) * 8];
        #pragma unroll
        for (int m = 0; m < 4; ++m)
            #pragma unroll
            for (int n = 0; n < 4; ++n)
                acc[m][n] = __builtin_amdgcn_mfma_f32_16x16x32_bf16(af[m], bfr[n], acc[m][n], 0, 0, 0);
        __syncthreads();
    }

    // epilogue: C/D layout col = lane&15, row = (lane>>4)*4 + r  [m89-verified]
    int colb = bn + wc*64 + (l & 15);
    #pragma unroll
    for (int m = 0; m < 4; ++m) {
        int row0 = bm + wr*64 + m*16 + (l >> 4)*4;
        #pragma unroll
        for (int r = 0; r < 4; ++r) {
            int row = row0 + r;
            int valid = 1;
            if (EPI) valid = get_valid(mask, row, u8);
            #pragma unroll
            for (int n = 0; n < 4; ++n) {
                int cc = colb + n*16;
                float val = acc[m][n][r];
                if (EPI) {
                    val = valid ? resid[(size_t)row*256 + cc] + val : 0.f;
                    ((float*)C)[(size_t)row*256 + cc] = val;
                } else {
                    ((unsigned short*)C)[(size_t)row*256 + cc] = f2bf(val);
                }
            }
        }
    }
}

// ---------------- fused: QKV GEMM (blocks 0..767) + KNN radix-select (768..4863) ----------------
// KNN: one wave per query row. Distances as sortable u32 keys; radix-select the
// rank-15 key tau (bit-by-bit, SALU ballot-counting), then ballot-compact the set
// {key < tau} + lowest-(t,lane) keys == tau. Same set as (d, lowest-index) top-k.
__global__ __launch_bounds__(256) void knn_qkv_fused(
    const float* __restrict__ xpos, int* __restrict__ idxout,
    const unsigned short* __restrict__ xpebf, const unsigned short* __restrict__ xbf,
    const unsigned short* __restrict__ WT,
    unsigned short* __restrict__ q, unsigned short* __restrict__ k,
    unsigned short* __restrict__ v) {
    __shared__ __align__(16) char smem[16384];
    int bid = blockIdx.x;
    if (bid < 768) {
        // ---- GEMM path ----
        int gx = bid & 127, gy = (bid >> 7) & 1, gz = bid >> 8;
        const unsigned short* A  = (gz == 2) ? xbf : xpebf;
        const unsigned short* BT = WT + (size_t)gz * 65536;
        unsigned short* C = (gz == 0) ? q : (gz == 1) ? k : v;
        gemm_mfma_core<0>(A, BT, C, nullptr, nullptr, 0, gx*128, gy*128, smem);
        return;
    }
    // ---- KNN path ----
    int kb = bid - 768;
    int nblk = kb & 255;         // 256 row-groups of 4
    int b = kb >> 8;             // batch
    float4* sp = (float4*)smem;
    for (int i = threadIdx.x; i < NN; i += 256) {
        const float* p = xpos + ((size_t)b*NN + i)*3;
        float px = p[0], py = p[1], pz = p[2];
        sp[i] = make_float4(px, py, pz, px*px + py*py + pz*pz);
    }
    __syncthreads();
    int wave = threadIdx.x >> 6, lane = threadIdx.x & 63;
    int n = nblk * 4 + wave;
    float4 qp = sp[n];
    unsigned key[16];
    #pragma unroll
    for (int t = 0; t < 16; ++t) {
        float4 pm = sp[lane + 64*t];
        float dot = qp.x*pm.x + qp.y*pm.y + qp.z*pm.z;
        float d2 = qp.w + pm.w - 2.f*dot;              // exact reference formula
        key[t] = __builtin_bit_cast(unsigned, fmaxf(d2, 0.f));
    }
    // radix-select tau = rank-15 (0-indexed) key
    unsigned prefix = 0;
    #pragma unroll 1
    for (int bit = 30; bit >= 0; --bit) {
        unsigned cand = prefix | (1u << bit);
        int c = 0;
        #pragma unroll
        for (int t = 0; t < 16; ++t)
            c += (int)__popcll(__ballot(key[t] < cand));
        if (c < 16) prefix = cand;    // tau >= cand: keep the bit
    }
    unsigned tau = prefix;
    // c1 = #keys strictly below tau (<= 15 by construction)
    int c1 = 0;
    #pragma unroll
    for (int t = 0; t < 16; ++t)
        c1 += (int)__popcll(__ballot(key[t] < tau));
    // compaction: lt keys fill [0,c1); eq keys (in ascending m = lane+64t order,
    // i.e. t-major lane-minor) fill [c1,16)
    int out_base = (b*NN + n) * KNBR;
    int lt_base = 0, eq_seen = 0;
    #pragma unroll
    for (int t = 0; t < 16; ++t) {
        bool lt = key[t] < tau;
        bool eq = key[t] == tau;
        unsigned long long blt = __ballot(lt);
        unsigned long long beq = __ballot(eq);
        if (lt) {
            int pos = lt_base + mbcnt64(blt);
            idxout[out_base + pos] = lane + 64*t;
        }
        int erank = eq_seen + mbcnt64(beq);
        if (eq && (c1 + erank) < 16) {
            idxout[out_base + c1 + erank] = lane + 64*t;
        }
        lt_base += (int)__popcll(blt);
        eq_seen += (int)__popcll(beq);
    }
}

__global__ __launch_bounds__(256) void gemm_out_mfma(
    const unsigned short* __restrict__ aobf, const unsigned short* __restrict__ WT,
    const float* __restrict__ x, const void* __restrict__ mask,
    const int* __restrict__ flag, float* __restrict__ out) {
    __shared__ __align__(16) char smem[16384];
    int u8 = *flag;
    gemm_mfma_core<1>(aobf, WT + (size_t)3 * 65536, out, x, mask, u8,
                      blockIdx.x * 128, blockIdx.y * 128, smem);
}

// ---------------- local attention: one wave per token, bf16 q/k/v ----------------
__global__ __launch_bounds__(256) void attn_kernel(
    const unsigned short* __restrict__ q, const unsigned short* __restrict__ k,
    const unsigned short* __restrict__ v, const int* __restrict__ idx,
    const void* __restrict__ mask, const int* __restrict__ flag,
    unsigned short* __restrict__ aobf) {
    __shared__ int   s_j[4][16];
    __shared__ float s_w[4][16][8];
    int u8 = *flag;
    int wave = threadIdx.x >> 6, lane = threadIdx.x & 63;
    // XCD-chunked swizzle: 4096 blocks -> 512 consecutive blocks per XCD
    int cpx = gridDim.x >> 3;
    int sb = ((int)blockIdx.x & 7) * cpx + ((int)blockIdx.x >> 3);
    int t = sb * 4 + wave;
    int b = t >> 10;
    int sub = lane & 3, nbr = lane >> 2;
    int j = idx[(size_t)t*KNBR + nbr];
    if (lane < 16) s_j[wave][lane] = idx[(size_t)t*KNBR + lane];
    int nv = get_valid(mask, b*NN + j, u8);
    const unsigned short* qb = q + (size_t)t*DD;
    const unsigned short* kb = k + ((size_t)(b*NN + j))*DD;

    float w[8];
    #pragma unroll
    for (int h = 0; h < 8; ++h) {
        bf16x8 qv = *(const bf16x8*)(qb + h*32 + sub*8);
        bf16x8 kv = *(const bf16x8*)(kb + h*32 + sub*8);
        float acc = 0.f;
        #pragma unroll
        for (int e = 0; e < 8; ++e)
            acc += bf2f((unsigned short)qv[e]) * bf2f((unsigned short)kv[e]);
        acc += __shfl_xor(acc, 1);
        acc += __shfl_xor(acc, 2);
        float s = nv ? acc * 0.17677669529663688f : -1e9f;   // 1/sqrt(32)
        float m = s;
        #pragma unroll
        for (int off = 4; off <= 32; off <<= 1) m = fmaxf(m, __shfl_xor(m, off));
        float e = __expf(s - m);
        float sum = e;
        #pragma unroll
        for (int off = 4; off <= 32; off <<= 1) sum += __shfl_xor(sum, off);
        w[h] = e / sum;
    }
    if (sub == 0) {
        #pragma unroll
        for (int h = 0; h < 8; ++h) s_w[wave][nbr][h] = w[h];
    }
    __syncthreads();

    // PV: channel c0 = lane*4 .. +3, head h = lane>>3
    int c0 = lane * 4;
    int h = lane >> 3;
    float o0 = 0.f, o1 = 0.f, o2 = 0.f, o3 = 0.f;
    #pragma unroll
    for (int kk = 0; kk < 16; ++kk) {
        int jj = s_j[wave][kk];
        float wk = s_w[wave][kk][h];
        u16x4 vv = *(const u16x4*)(v + ((size_t)(b*NN + jj))*DD + c0);
        o0 += wk * bf2f(vv[0]);
        o1 += wk * bf2f(vv[1]);
        o2 += wk * bf2f(vv[2]);
        o3 += wk * bf2f(vv[3]);
    }
    u16x4 st;
    st[0] = f2bf(o0); st[1] = f2bf(o1); st[2] = f2bf(o2); st[3] = f2bf(o3);
    *(u16x4*)(aobf + (size_t)t*DD + c0) = st;
}

extern "C" void kernel_launch(void* const* d_in, const int* in_sizes, int n_in,
                              void* d_out, int out_size, void* d_ws, size_t ws_size,
                              hipStream_t stream) {
    const float* x    = (const float*)d_in[0];
    const float* xpos = (const float*)d_in[1];
    const void*  mask = d_in[2];
    const float* Wq   = (const float*)d_in[3];
    const float* Wk   = (const float*)d_in[4];
    const float* Wv   = (const float*)d_in[5];
    const float* Wo   = (const float*)d_in[6];
    float* out = (float*)d_out;
    char*  ws  = (char*)d_ws;
    if (ws_size < WS_NEED) return;

    int*            flag  = (int*)           (ws + OFF_FLAG);
    unsigned short* xpebf = (unsigned short*)(ws + OFF_XPE);
    unsigned short* xbf   = (unsigned short*)(ws + OFF_XBF);
    unsigned short* WT    = (unsigned short*)(ws + OFF_WT);
    unsigned short* q     = (unsigned short*)(ws + OFF_Q);
    unsigned short* k     = (unsigned short*)(ws + OFF_K);
    unsigned short* v     = (unsigned short*)(ws + OFF_V);
    unsigned short* aobf  = (unsigned short*)(ws + OFF_AO);
    int*            idx   = (int*)           (ws + OFF_IDX);

    detect_cvtw_kernel<<<1025, 256, 0, stream>>>((const unsigned*)mask, flag,
                                                 Wq, Wk, Wv, Wo, WT);
    pe_cvt_kernel<<<MM/2, 256, 0, stream>>>(x, xpos, mask, flag, xpebf, xbf);
    knn_qkv_fused<<<768 + 4096, 256, 0, stream>>>(xpos, idx, xpebf, xbf, WT, q, k, v);
    attn_kernel<<<MM/4, 256, 0, stream>>>(q, k, v, idx, mask, flag, aobf);
    gemm_out_mfma<<<dim3(128, 2), 256, 0, stream>>>(aobf, WT, x, mask, flag, out);
}

// Round 6
// 111.357 us; speedup vs baseline: 2.3845x; 1.1449x over previous
//
#include <hip/hip_runtime.h>
#include <math.h>

// Problem constants
#define BB 16
#define NN 1024
#define DD 256
#define HH 8
#define DHH 32
#define KNBR 16
#define MM (BB*NN)   // 16384 tokens

typedef __attribute__((ext_vector_type(8))) short  bf16x8;
typedef __attribute__((ext_vector_type(4))) float  f32x4;
typedef __attribute__((ext_vector_type(2))) unsigned short u16x2;
typedef __attribute__((ext_vector_type(4))) unsigned short u16x4;

// ---------------- workspace layout (bytes) ----------------
#define OFF_FLAG 0
#define OFF_XPE  ((size_t)256)                          // bf16 x+pe (8 MB) — aliased by aobf later
#define OFF_XBF  (OFF_XPE + (size_t)MM*DD*2)            // bf16 x    (8 MB)
#define OFF_WT   (OFF_XBF + (size_t)MM*DD*2)            // bf16 WT[4][256][256] (512 KB)
#define OFF_Q    (OFF_WT  + (size_t)4*DD*DD*2)          // bf16 q (8 MB)
#define OFF_K    (OFF_Q   + (size_t)MM*DD*2)
#define OFF_V    (OFF_K   + (size_t)MM*DD*2)
#define OFF_AO   OFF_XPE                                // bf16 attn-out reuses xpe region
#define OFF_IDX  (OFF_V   + (size_t)MM*DD*2)
#define WS_NEED  (OFF_IDX + (size_t)MM*KNBR*4)

// ---------------- bf16 helpers ----------------
__device__ __forceinline__ float bf2f(unsigned short u) {
    unsigned x = ((unsigned)u) << 16;
    return __builtin_bit_cast(float, x);
}
__device__ __forceinline__ unsigned short f2bf(float f) {
    unsigned x = __builtin_bit_cast(unsigned, f);
    unsigned r = (x + 0x7fffu + ((x >> 16) & 1u)) >> 16;   // RNE
    return (unsigned short)r;
}
__device__ __forceinline__ int mbcnt64(unsigned long long b) {
    // popcount of b restricted to lanes strictly below this lane
    return __builtin_amdgcn_mbcnt_hi((unsigned)(b >> 32),
           __builtin_amdgcn_mbcnt_lo((unsigned)b, 0));
}

__device__ __forceinline__ int get_valid(const void* m, int i, int u8) {
    if (u8) return ((const unsigned char*)m)[i] != 0;
    return ((const unsigned*)m)[i] != 0u;
}

// ---------------- fused: mask detect (block 0) + weight cvt/transpose ----------------
// flag: 0 = 4-byte elements (int32/float32), 1 = 1-byte (uint8 bool)
__global__ __launch_bounds__(256) void detect_cvtw_kernel(
    const unsigned* __restrict__ mraw, int* __restrict__ flag,
    const float* __restrict__ Wq, const float* __restrict__ Wk,
    const float* __restrict__ Wv, const float* __restrict__ Wo,
    unsigned short* __restrict__ WT) {
    int bid = blockIdx.x;
    if (bid == 0) {
        __shared__ int s_u8, s_f32;
        if (threadIdx.x == 0) { s_u8 = 0; s_f32 = 0; }
        __syncthreads();
        int u8 = 0, f32 = 0;
        for (int i = threadIdx.x; i < 4096; i += 256) {
            unsigned w = mraw[i];
            if (w == 0x3f800000u) f32 = 1;
            else if (w > 1u) u8 = 1;
        }
        if (u8)  atomicOr(&s_u8, 1);
        if (f32) atomicOr(&s_f32, 1);
        __syncthreads();
        if (threadIdx.x == 0) *flag = (s_f32 ? 0 : (s_u8 ? 1 : 0));
    } else {
        int g = bid - 1;                 // 0..1023
        int wsel = g >> 8;               // 0..3
        int kk = g & 255;                // 0..255
        const float* W = (wsel == 0) ? Wq : (wsel == 1) ? Wk : (wsel == 2) ? Wv : Wo;
        int n = threadIdx.x;
        WT[(size_t)wsel*65536 + (size_t)n*256 + kk] = f2bf(W[(size_t)kk*256 + n]);
    }
}

// ---------------- PE + bf16 conversion of (x+pe) and x ----------------
__global__ __launch_bounds__(256) void pe_cvt_kernel(
    const float* __restrict__ x, const float* __restrict__ xpos,
    const void* __restrict__ mask, const int* __restrict__ flag,
    unsigned short* __restrict__ xpebf, unsigned short* __restrict__ xbf) {
    int tid = threadIdx.x;
    int t = blockIdx.x * 2 + (tid >> 7);
    int p = tid & 127;
    int u8 = *flag;
    int valid = get_valid(mask, t, u8);
    int half = p >> 6;             // 0 -> y channels [0,128), 1 -> x channels [128,256)
    int j = p & 63;
    float pos = xpos[(size_t)t*3 + (half ? 0 : 1)];
    float recip = 6.2831853071795864f * exp2f(-(float)j * 0.20762050593045952f);
    float th = pos * recip;
    float s, c;
    __sincosf(th, &s, &c);
    if (!valid) { s = 0.f; c = 0.f; }
    size_t o = (size_t)t*DD + half*128 + 2*j;
    float2 xv = *(const float2*)(x + o);
    u16x2 xb; xb[0] = f2bf(xv.x);     xb[1] = f2bf(xv.y);
    u16x2 xp; xp[0] = f2bf(xv.x + s); xp[1] = f2bf(xv.y + c);
    *(u16x2*)(xbf + o)   = xb;
    *(u16x2*)(xpebf + o) = xp;
}

// ---------------- bf16 MFMA GEMM core: C[M,256] = A[M,256] @ W[256,256] ----------------
// Tile 128x128, BK=32, 4 waves, each wave 64x64 = 4x4 fragments of 16x16x32.
template<int EPI>
__device__ __forceinline__ void gemm_mfma_core(
    const unsigned short* __restrict__ A, const unsigned short* __restrict__ BT,
    void* __restrict__ C, const float* __restrict__ resid,
    const void* __restrict__ mask, int u8, int bm, int bn, char* smem) {
    unsigned short (*As)[32] = (unsigned short (*)[32])smem;
    unsigned short (*Bs)[32] = (unsigned short (*)[32])(smem + 8192);
    int tid = threadIdx.x;
    int w = tid >> 6, l = tid & 63;
    int wr = w >> 1, wc = w & 1;

    f32x4 acc[4][4] = {};

    for (int kt = 0; kt < 8; ++kt) {
        #pragma unroll
        for (int j = 0; j < 2; ++j) {
            int c  = (w + j*4)*64 + l;        // 0..511
            int row = c >> 2;                 // 0..127
            int cb  = (c & 3) * 16;           // byte col within 64B row
            const char* ga = (const char*)A + ((size_t)(bm + row)*256 + kt*32)*2 + cb;
            char* la = (char*)As + (size_t)(w + j*4)*1024;   // wave-uniform dest
            __builtin_amdgcn_global_load_lds(
                (const __attribute__((address_space(1))) unsigned*)ga,
                (__attribute__((address_space(3))) unsigned*)la, 16, 0, 0);
            const char* gb = (const char*)BT + ((size_t)(bn + row)*256 + kt*32)*2 + cb;
            char* lb = (char*)Bs + (size_t)(w + j*4)*1024;
            __builtin_amdgcn_global_load_lds(
                (const __attribute__((address_space(1))) unsigned*)gb,
                (__attribute__((address_space(3))) unsigned*)lb, 16, 0, 0);
        }
        __syncthreads();

        bf16x8 af[4], bfr[4];
        #pragma unroll
        for (int m = 0; m < 4; ++m)
            af[m] = *(const bf16x8*)&As[wr*64 + m*16 + (l & 15)][(l >> 4) * 8];
        #pragma unroll
        for (int n = 0; n < 4; ++n)
            bfr[n] = *(const bf16x8*)&Bs[wc*64 + n*16 + (l & 15)][(l >> 4) * 8];
        #pragma unroll
        for (int m = 0; m < 4; ++m)
            #pragma unroll
            for (int n = 0; n < 4; ++n)
                acc[m][n] = __builtin_amdgcn_mfma_f32_16x16x32_bf16(af[m], bfr[n], acc[m][n], 0, 0, 0);
        __syncthreads();
    }

    // epilogue: C/D layout col = lane&15, row = (lane>>4)*4 + r  [m89-verified]
    int colb = bn + wc*64 + (l & 15);
    #pragma unroll
    for (int m = 0; m < 4; ++m) {
        int row0 = bm + wr*64 + m*16 + (l >> 4)*4;
        #pragma unroll
        for (int r = 0; r < 4; ++r) {
            int row = row0 + r;
            int valid = 1;
            if (EPI) valid = get_valid(mask, row, u8);
            #pragma unroll
            for (int n = 0; n < 4; ++n) {
                int cc = colb + n*16;
                float val = acc[m][n][r];
                if (EPI) {
                    val = valid ? resid[(size_t)row*256 + cc] + val : 0.f;
                    ((float*)C)[(size_t)row*256 + cc] = val;
                } else {
                    ((unsigned short*)C)[(size_t)row*256 + cc] = f2bf(val);
                }
            }
        }
    }
}

// ---------------- fused: QKV GEMM (blocks 0..767) + KNN (768..4863) ----------------
// KNN per wave: threshold-filter via bitonic-sorted lane minima (tau = 16th smallest),
// ballot-compact candidates {d<=tau} as unique u64 keys (d2_bits<<10|index), bitonic
// sort 64 keys -> lanes 0..15 = exact (d, lowest-index) top-16 (reference semantics,
// tie-exact). Fallback to iterative argmin if candidate count > 64 (pathological).
__global__ __launch_bounds__(256) void knn_qkv_fused(
    const float* __restrict__ xpos, int* __restrict__ idxout,
    const unsigned short* __restrict__ xpebf, const unsigned short* __restrict__ xbf,
    const unsigned short* __restrict__ WT,
    unsigned short* __restrict__ q, unsigned short* __restrict__ k,
    unsigned short* __restrict__ v) {
    __shared__ __align__(16) char smem[18432];   // GEMM: 16 KB tiles; KNN: 16 KB pos + 2 KB cand
    int bid = blockIdx.x;
    if (bid < 768) {
        // ---- GEMM path ----
        int gx = bid & 127, gy = (bid >> 7) & 1, gz = bid >> 8;
        const unsigned short* A  = (gz == 2) ? xbf : xpebf;
        const unsigned short* BT = WT + (size_t)gz * 65536;
        unsigned short* C = (gz == 0) ? q : (gz == 1) ? k : v;
        gemm_mfma_core<0>(A, BT, C, nullptr, nullptr, 0, gx*128, gy*128, smem);
        return;
    }
    // ---- KNN path ----
    int kb = bid - 768;
    int nblk = kb & 255;         // 256 row-groups of 4
    int b = kb >> 8;             // batch
    float4* sp = (float4*)smem;
    for (int i = threadIdx.x; i < NN; i += 256) {
        const float* p = xpos + ((size_t)b*NN + i)*3;
        float px = p[0], py = p[1], pz = p[2];
        sp[i] = make_float4(px, py, pz, px*px + py*py + pz*pz);
    }
    __syncthreads();
    int wave = threadIdx.x >> 6, lane = threadIdx.x & 63;
    int n = nblk * 4 + wave;
    float4 qp = sp[n];
    float d[16];
    #pragma unroll
    for (int t = 0; t < 16; ++t) {
        float4 pm = sp[lane + 64*t];
        float dot = qp.x*pm.x + qp.y*pm.y + qp.z*pm.z;
        float d2 = qp.w + pm.w - 2.f*dot;              // exact reference formula
        d[t] = fmaxf(d2, 0.f);
    }
    // 1) per-lane min (value only)
    float lmin = d[0];
    #pragma unroll
    for (int t = 1; t < 16; ++t) lmin = fminf(lmin, d[t]);
    // 2) bitonic sort the 64 lane minima ascending; tau = 16th smallest
    float xs = lmin;
    #pragma unroll
    for (int kk = 2; kk <= 64; kk <<= 1) {
        #pragma unroll
        for (int j = kk >> 1; j >= 1; j >>= 1) {
            float vv = __shfl_xor(xs, j);
            bool up = ((lane & kk) == 0);
            bool lower = ((lane & j) == 0);
            xs = (up == lower) ? fminf(xs, vv) : fmaxf(xs, vv);
        }
    }
    float tau = __shfl(xs, 15);
    // 3) count candidates {d <= tau}  (>= 16 by construction)
    int T = 0;
    #pragma unroll
    for (int t = 0; t < 16; ++t) T += (d[t] <= tau) ? 1 : 0;
    #pragma unroll
    for (int off = 1; off <= 32; off <<= 1) T += __shfl_xor(T, off);

    bool fast = (T <= 64);          // wave-uniform
    unsigned long long* cand = (unsigned long long*)(smem + 16384) + wave*64;
    if (fast) {
        int base = 0;
        #pragma unroll
        for (int t = 0; t < 16; ++t) {
            bool c = (d[t] <= tau);
            unsigned long long bb = __ballot(c);
            if (c) {
                unsigned bits = __builtin_bit_cast(unsigned, d[t]);
                unsigned long long key = ((unsigned long long)bits << 10)
                                       | (unsigned)(lane + 64*t);
                cand[base + mbcnt64(bb)] = key;
            }
            base += (int)__popcll(bb);
        }
    }
    __syncthreads();   // block-wide: reached by all 4 waves regardless of 'fast'

    int out_base = (b*NN + n) * KNBR;
    if (fast) {
        unsigned long long key = (lane < T) ? cand[lane] : ~0ULL;
        // bitonic sort 64 u64 keys ascending
        #pragma unroll
        for (int kk = 2; kk <= 64; kk <<= 1) {
            #pragma unroll
            for (int j = kk >> 1; j >= 1; j >>= 1) {
                unsigned lo = (unsigned)key, hi = (unsigned)(key >> 32);
                unsigned vlo = (unsigned)__shfl_xor((int)lo, j);
                unsigned vhi = (unsigned)__shfl_xor((int)hi, j);
                unsigned long long vkey = ((unsigned long long)vhi << 32) | vlo;
                bool up = ((lane & kk) == 0);
                bool lower = ((lane & j) == 0);
                bool takemin = (up == lower);
                bool less = (key < vkey);
                key = (takemin == less) ? key : vkey;
            }
        }
        if (lane < KNBR) idxout[out_base + lane] = (int)(key & 1023u);
    } else {
        // exact iterative fallback (proven R3 path)
        #pragma unroll 1
        for (int it = 0; it < KNBR; ++it) {
            float bd = 3.4e38f; int bm = 1 << 30;
            #pragma unroll
            for (int t = 0; t < 16; ++t)
                if (d[t] < bd) { bd = d[t]; bm = lane + 64*t; }
            #pragma unroll
            for (int off = 32; off >= 1; off >>= 1) {
                float od = __shfl_xor(bd, off);
                int   om = __shfl_xor(bm, off);
                if (od < bd || (od == bd && om < bm)) { bd = od; bm = om; }
            }
            if (lane == 0) idxout[out_base + it] = bm;
            int sel = bm >> 6;
            int mine = ((bm & 63) == lane);
            #pragma unroll
            for (int t = 0; t < 16; ++t)
                if (mine && t == sel) d[t] = 3.4e38f;
        }
    }
}

__global__ __launch_bounds__(256) void gemm_out_mfma(
    const unsigned short* __restrict__ aobf, const unsigned short* __restrict__ WT,
    const float* __restrict__ x, const void* __restrict__ mask,
    const int* __restrict__ flag, float* __restrict__ out) {
    __shared__ __align__(16) char smem[16384];
    int u8 = *flag;
    gemm_mfma_core<1>(aobf, WT + (size_t)3 * 65536, out, x, mask, u8,
                      blockIdx.x * 128, blockIdx.y * 128, smem);
}

// ---------------- local attention: one wave per token, bf16 q/k/v ----------------
__global__ __launch_bounds__(256) void attn_kernel(
    const unsigned short* __restrict__ q, const unsigned short* __restrict__ k,
    const unsigned short* __restrict__ v, const int* __restrict__ idx,
    const void* __restrict__ mask, const int* __restrict__ flag,
    unsigned short* __restrict__ aobf) {
    __shared__ int   s_j[4][16];
    __shared__ float s_w[4][16][8];
    int u8 = *flag;
    int wave = threadIdx.x >> 6, lane = threadIdx.x & 63;
    // XCD-chunked swizzle: 4096 blocks -> 512 consecutive blocks per XCD
    int cpx = gridDim.x >> 3;
    int sb = ((int)blockIdx.x & 7) * cpx + ((int)blockIdx.x >> 3);
    int t = sb * 4 + wave;
    int b = t >> 10;
    int sub = lane & 3, nbr = lane >> 2;
    int j = idx[(size_t)t*KNBR + nbr];
    if (lane < 16) s_j[wave][lane] = idx[(size_t)t*KNBR + lane];
    int nv = get_valid(mask, b*NN + j, u8);
    const unsigned short* qb = q + (size_t)t*DD;
    const unsigned short* kb = k + ((size_t)(b*NN + j))*DD;

    float w[8];
    #pragma unroll
    for (int h = 0; h < 8; ++h) {
        bf16x8 qv = *(const bf16x8*)(qb + h*32 + sub*8);
        bf16x8 kv = *(const bf16x8*)(kb + h*32 + sub*8);
        float acc = 0.f;
        #pragma unroll
        for (int e = 0; e < 8; ++e)
            acc += bf2f((unsigned short)qv[e]) * bf2f((unsigned short)kv[e]);
        acc += __shfl_xor(acc, 1);
        acc += __shfl_xor(acc, 2);
        float s = nv ? acc * 0.17677669529663688f : -1e9f;   // 1/sqrt(32)
        float m = s;
        #pragma unroll
        for (int off = 4; off <= 32; off <<= 1) m = fmaxf(m, __shfl_xor(m, off));
        float e = __expf(s - m);
        float sum = e;
        #pragma unroll
        for (int off = 4; off <= 32; off <<= 1) sum += __shfl_xor(sum, off);
        w[h] = e / sum;
    }
    if (sub == 0) {
        #pragma unroll
        for (int h = 0; h < 8; ++h) s_w[wave][nbr][h] = w[h];
    }
    __syncthreads();

    // PV: channel c0 = lane*4 .. +3, head h = lane>>3
    int c0 = lane * 4;
    int h = lane >> 3;
    float o0 = 0.f, o1 = 0.f, o2 = 0.f, o3 = 0.f;
    #pragma unroll
    for (int kk = 0; kk < 16; ++kk) {
        int jj = s_j[wave][kk];
        float wk = s_w[wave][kk][h];
        u16x4 vv = *(const u16x4*)(v + ((size_t)(b*NN + jj))*DD + c0);
        o0 += wk * bf2f(vv[0]);
        o1 += wk * bf2f(vv[1]);
        o2 += wk * bf2f(vv[2]);
        o3 += wk * bf2f(vv[3]);
    }
    u16x4 st;
    st[0] = f2bf(o0); st[1] = f2bf(o1); st[2] = f2bf(o2); st[3] = f2bf(o3);
    *(u16x4*)(aobf + (size_t)t*DD + c0) = st;
}

extern "C" void kernel_launch(void* const* d_in, const int* in_sizes, int n_in,
                              void* d_out, int out_size, void* d_ws, size_t ws_size,
                              hipStream_t stream) {
    const float* x    = (const float*)d_in[0];
    const float* xpos = (const float*)d_in[1];
    const void*  mask = d_in[2];
    const float* Wq   = (const float*)d_in[3];
    const float* Wk   = (const float*)d_in[4];
    const float* Wv   = (const float*)d_in[5];
    const float* Wo   = (const float*)d_in[6];
    float* out = (float*)d_out;
    char*  ws  = (char*)d_ws;
    if (ws_size < WS_NEED) return;

    int*            flag  = (int*)           (ws + OFF_FLAG);
    unsigned short* xpebf = (unsigned short*)(ws + OFF_XPE);
    unsigned short* xbf   = (unsigned short*)(ws + OFF_XBF);
    unsigned short* WT    = (unsigned short*)(ws + OFF_WT);
    unsigned short* q     = (unsigned short*)(ws + OFF_Q);
    unsigned short* k     = (unsigned short*)(ws + OFF_K);
    unsigned short* v     = (unsigned short*)(ws + OFF_V);
    unsigned short* aobf  = (unsigned short*)(ws + OFF_AO);
    int*            idx   = (int*)           (ws + OFF_IDX);

    detect_cvtw_kernel<<<1025, 256, 0, stream>>>((const unsigned*)mask, flag,
                                                 Wq, Wk, Wv, Wo, WT);
    pe_cvt_kernel<<<MM/2, 256, 0, stream>>>(x, xpos, mask, flag, xpebf, xbf);
    knn_qkv_fused<<<768 + 4096, 256, 0, stream>>>(xpos, idx, xpebf, xbf, WT, q, k, v);
    attn_kernel<<<MM/4, 256, 0, stream>>>(q, k, v, idx, mask, flag, aobf);
    gemm_out_mfma<<<dim3(128, 2), 256, 0, stream>>>(aobf, WT, x, mask, flag, out);
}

// Round 7
// 92.001 us; speedup vs baseline: 2.8861x; 1.2104x over previous
//
#include <hip/hip_runtime.h>
#include <math.h>

// Problem constants
#define BB 16
#define NN 1024
#define DD 256
#define HH 8
#define DHH 32
#define KNBR 16
#define MM (BB*NN)   // 16384 tokens

typedef __attribute__((ext_vector_type(8))) short  bf16x8;
typedef __attribute__((ext_vector_type(4))) float  f32x4;
typedef __attribute__((ext_vector_type(2))) unsigned short u16x2;
typedef __attribute__((ext_vector_type(4))) unsigned short u16x4;

// ---------------- workspace layout (bytes) ----------------
#define OFF_FLAG 0
#define OFF_XPE  ((size_t)256)                          // bf16 x+pe (8 MB) — aliased by aobf later
#define OFF_XBF  (OFF_XPE + (size_t)MM*DD*2)            // bf16 x    (8 MB)
#define OFF_WT   (OFF_XBF + (size_t)MM*DD*2)            // bf16 WT[4][256][256] (512 KB)
#define OFF_Q    (OFF_WT  + (size_t)4*DD*DD*2)          // bf16 q (8 MB)
#define OFF_K    (OFF_Q   + (size_t)MM*DD*2)
#define OFF_V    (OFF_K   + (size_t)MM*DD*2)
#define OFF_AO   OFF_XPE                                // bf16 attn-out reuses xpe region
#define OFF_IDX  (OFF_V   + (size_t)MM*DD*2)
#define WS_NEED  (OFF_IDX + (size_t)MM*KNBR*4)

// ---------------- bf16 helpers ----------------
__device__ __forceinline__ float bf2f(unsigned short u) {
    unsigned x = ((unsigned)u) << 16;
    return __builtin_bit_cast(float, x);
}
__device__ __forceinline__ unsigned short f2bf(float f) {
    unsigned x = __builtin_bit_cast(unsigned, f);
    unsigned r = (x + 0x7fffu + ((x >> 16) & 1u)) >> 16;   // RNE
    return (unsigned short)r;
}
__device__ __forceinline__ int mbcnt64(unsigned long long b) {
    // popcount of b restricted to lanes strictly below this lane
    return __builtin_amdgcn_mbcnt_hi((unsigned)(b >> 32),
           __builtin_amdgcn_mbcnt_lo((unsigned)b, 0));
}

__device__ __forceinline__ int get_valid(const void* m, int i, int u8) {
    if (u8) return ((const unsigned char*)m)[i] != 0;
    return ((const unsigned*)m)[i] != 0u;
}

// ---------------- fused: mask detect (block 0) + weight cvt/transpose ----------------
// flag: 0 = 4-byte elements (int32/float32), 1 = 1-byte (uint8 bool)
__global__ __launch_bounds__(256) void detect_cvtw_kernel(
    const unsigned* __restrict__ mraw, int* __restrict__ flag,
    const float* __restrict__ Wq, const float* __restrict__ Wk,
    const float* __restrict__ Wv, const float* __restrict__ Wo,
    unsigned short* __restrict__ WT) {
    int bid = blockIdx.x;
    if (bid == 0) {
        __shared__ int s_u8, s_f32;
        if (threadIdx.x == 0) { s_u8 = 0; s_f32 = 0; }
        __syncthreads();
        int u8 = 0, f32 = 0;
        for (int i = threadIdx.x; i < 4096; i += 256) {
            unsigned w = mraw[i];
            if (w == 0x3f800000u) f32 = 1;
            else if (w > 1u) u8 = 1;
        }
        if (u8)  atomicOr(&s_u8, 1);
        if (f32) atomicOr(&s_f32, 1);
        __syncthreads();
        if (threadIdx.x == 0) *flag = (s_f32 ? 0 : (s_u8 ? 1 : 0));
    } else {
        int g = bid - 1;                 // 0..1023
        int wsel = g >> 8;               // 0..3
        int kk = g & 255;                // 0..255
        const float* W = (wsel == 0) ? Wq : (wsel == 1) ? Wk : (wsel == 2) ? Wv : Wo;
        int n = threadIdx.x;
        WT[(size_t)wsel*65536 + (size_t)n*256 + kk] = f2bf(W[(size_t)kk*256 + n]);
    }
}

// ---------------- PE + bf16 conversion of (x+pe) and x ----------------
__global__ __launch_bounds__(256) void pe_cvt_kernel(
    const float* __restrict__ x, const float* __restrict__ xpos,
    const void* __restrict__ mask, const int* __restrict__ flag,
    unsigned short* __restrict__ xpebf, unsigned short* __restrict__ xbf) {
    int tid = threadIdx.x;
    int t = blockIdx.x * 2 + (tid >> 7);
    int p = tid & 127;
    int u8 = *flag;
    int valid = get_valid(mask, t, u8);
    int half = p >> 6;             // 0 -> y channels [0,128), 1 -> x channels [128,256)
    int j = p & 63;
    float pos = xpos[(size_t)t*3 + (half ? 0 : 1)];
    float recip = 6.2831853071795864f * exp2f(-(float)j * 0.20762050593045952f);
    float th = pos * recip;
    float s, c;
    __sincosf(th, &s, &c);
    if (!valid) { s = 0.f; c = 0.f; }
    size_t o = (size_t)t*DD + half*128 + 2*j;
    float2 xv = *(const float2*)(x + o);
    u16x2 xb; xb[0] = f2bf(xv.x);     xb[1] = f2bf(xv.y);
    u16x2 xp; xp[0] = f2bf(xv.x + s); xp[1] = f2bf(xv.y + c);
    *(u16x2*)(xbf + o)   = xb;
    *(u16x2*)(xpebf + o) = xp;
}

// ---------------- KNN standalone: one wave per query row, 8 waves/SIMD ----------------
// tau-filter (bitonic-sorted lane minima), compact candidate VALUES (u32, since
// d2>=0 bit order == float order), bitonic sort values -> exact v16; emit
// {d < v16} + lowest-index ties == v16 (reference (d, lowest-index) semantics).
// Fallback: proven iterative argmin if candidate count > 64.
__global__ __launch_bounds__(256, 8) void knn_kernel(
    const float* __restrict__ xpos, int* __restrict__ idxout) {
    __shared__ float4   sp[NN];          // 16 KB
    __shared__ unsigned scand[4][64];    // 1 KB
    int nblk = blockIdx.x;   // 0..255
    int b    = blockIdx.y;   // 0..15
    for (int i = threadIdx.x; i < NN; i += 256) {
        const float* p = xpos + ((size_t)b*NN + i)*3;
        float px = p[0], py = p[1], pz = p[2];
        sp[i] = make_float4(px, py, pz, px*px + py*py + pz*pz);
    }
    __syncthreads();
    int wave = threadIdx.x >> 6, lane = threadIdx.x & 63;
    int n = nblk * 4 + wave;
    float4 qp = sp[n];
    float d[16];
    #pragma unroll
    for (int t = 0; t < 16; ++t) {
        float4 pm = sp[lane + 64*t];
        float dot = qp.x*pm.x + qp.y*pm.y + qp.z*pm.z;
        float d2 = qp.w + pm.w - 2.f*dot;              // exact reference formula
        d[t] = fmaxf(d2, 0.f);
    }
    // 1) per-lane min
    float lmin = d[0];
    #pragma unroll
    for (int t = 1; t < 16; ++t) lmin = fminf(lmin, d[t]);
    // 2) bitonic sort 64 lane minima ascending; tau = 16th smallest (>= v16)
    float xs = lmin;
    #pragma unroll
    for (int kk = 2; kk <= 64; kk <<= 1) {
        #pragma unroll
        for (int j = kk >> 1; j >= 1; j >>= 1) {
            float vv = __shfl_xor(xs, j);
            bool up = ((lane & kk) == 0);
            bool lower = ((lane & j) == 0);
            xs = (up == lower) ? fminf(xs, vv) : fmaxf(xs, vv);
        }
    }
    float tau = __shfl(xs, 15);
    // 3) candidate count
    int T = 0;
    #pragma unroll
    for (int t = 0; t < 16; ++t) T += (d[t] <= tau) ? 1 : 0;
    #pragma unroll
    for (int off = 1; off <= 32; off <<= 1) T += __shfl_xor(T, off);

    bool fast = (T <= 64);          // wave-uniform
    if (fast) {
        int base = 0;
        #pragma unroll
        for (int t = 0; t < 16; ++t) {
            bool c = (d[t] <= tau);
            unsigned long long bb = __ballot(c);
            if (c) scand[wave][base + mbcnt64(bb)] = __builtin_bit_cast(unsigned, d[t]);
            base += (int)__popcll(bb);
        }
    }
    __syncthreads();   // block-wide: reached by all 4 waves regardless of 'fast'

    int out_base = (b*NN + n) * KNBR;
    if (fast) {
        unsigned key = (lane < T) ? scand[wave][lane] : 0xFFFFFFFFu;
        // bitonic sort 64 u32 values ascending (1 shuffle per step)
        #pragma unroll
        for (int kk = 2; kk <= 64; kk <<= 1) {
            #pragma unroll
            for (int j = kk >> 1; j >= 1; j >>= 1) {
                unsigned vv = (unsigned)__shfl_xor((int)key, j);
                bool up = ((lane & kk) == 0);
                bool lower = ((lane & j) == 0);
                bool takemin = (up == lower);
                key = (takemin == (key < vv)) ? key : vv;
            }
        }
        unsigned tau2 = (unsigned)__shfl((int)key, 15);   // exact v16 (u32 == f32 order)
        // c1 = global |{d < v16}|; valid because {d < v16} subset of candidates
        int c1 = (int)__popcll(__ballot(key < tau2));
        // emit: strict-smaller anywhere, then lowest-index ties at v16 fill the rest.
        // m = lane + 64*t is ascending in (t, lane) order -> index-exact ties.
        int lt_base = 0, eq_seen = 0;
        #pragma unroll
        for (int t = 0; t < 16; ++t) {
            unsigned du = __builtin_bit_cast(unsigned, d[t]);
            bool lt = du < tau2;
            bool eq = du == tau2;
            unsigned long long blt = __ballot(lt);
            unsigned long long beq = __ballot(eq);
            if (lt) idxout[out_base + lt_base + mbcnt64(blt)] = lane + 64*t;
            int er = eq_seen + mbcnt64(beq);
            if (eq && (c1 + er) < KNBR) idxout[out_base + c1 + er] = lane + 64*t;
            lt_base += (int)__popcll(blt);
            eq_seen += (int)__popcll(beq);
        }
    } else {
        // exact iterative fallback (proven R3 path)
        #pragma unroll 1
        for (int it = 0; it < KNBR; ++it) {
            float bd = 3.4e38f; int bm = 1 << 30;
            #pragma unroll
            for (int t = 0; t < 16; ++t)
                if (d[t] < bd) { bd = d[t]; bm = lane + 64*t; }
            #pragma unroll
            for (int off = 32; off >= 1; off >>= 1) {
                float od = __shfl_xor(bd, off);
                int   om = __shfl_xor(bm, off);
                if (od < bd || (od == bd && om < bm)) { bd = od; bm = om; }
            }
            if (lane == 0) idxout[out_base + it] = bm;
            int sel = bm >> 6;
            int mine = ((bm & 63) == lane);
            #pragma unroll
            for (int t = 0; t < 16; ++t)
                if (mine && t == sel) d[t] = 3.4e38f;
        }
    }
}

// ---------------- bf16 MFMA GEMM core: C[M,256] = A[M,256] @ W[256,256] ----------------
// Tile 128x128, BK=32, 4 waves, each wave 64x64 = 4x4 fragments of 16x16x32.
template<int EPI>
__device__ __forceinline__ void gemm_mfma_core(
    const unsigned short* __restrict__ A, const unsigned short* __restrict__ BT,
    void* __restrict__ C, const float* __restrict__ resid,
    const void* __restrict__ mask, int u8, int bm, int bn, char* smem) {
    unsigned short (*As)[32] = (unsigned short (*)[32])smem;
    unsigned short (*Bs)[32] = (unsigned short (*)[32])(smem + 8192);
    int tid = threadIdx.x;
    int w = tid >> 6, l = tid & 63;
    int wr = w >> 1, wc = w & 1;

    f32x4 acc[4][4] = {};

    for (int kt = 0; kt < 8; ++kt) {
        #pragma unroll
        for (int j = 0; j < 2; ++j) {
            int c  = (w + j*4)*64 + l;        // 0..511
            int row = c >> 2;                 // 0..127
            int cb  = (c & 3) * 16;           // byte col within 64B row
            const char* ga = (const char*)A + ((size_t)(bm + row)*256 + kt*32)*2 + cb;
            char* la = (char*)As + (size_t)(w + j*4)*1024;   // wave-uniform dest
            __builtin_amdgcn_global_load_lds(
                (const __attribute__((address_space(1))) unsigned*)ga,
                (__attribute__((address_space(3))) unsigned*)la, 16, 0, 0);
            const char* gb = (const char*)BT + ((size_t)(bn + row)*256 + kt*32)*2 + cb;
            char* lb = (char*)Bs + (size_t)(w + j*4)*1024;
            __builtin_amdgcn_global_load_lds(
                (const __attribute__((address_space(1))) unsigned*)gb,
                (__attribute__((address_space(3))) unsigned*)lb, 16, 0, 0);
        }
        __syncthreads();

        bf16x8 af[4], bfr[4];
        #pragma unroll
        for (int m = 0; m < 4; ++m)
            af[m] = *(const bf16x8*)&As[wr*64 + m*16 + (l & 15)][(l >> 4) * 8];
        #pragma unroll
        for (int n = 0; n < 4; ++n)
            bfr[n] = *(const bf16x8*)&Bs[wc*64 + n*16 + (l & 15)][(l >> 4) * 8];
        #pragma unroll
        for (int m = 0; m < 4; ++m)
            #pragma unroll
            for (int n = 0; n < 4; ++n)
                acc[m][n] = __builtin_amdgcn_mfma_f32_16x16x32_bf16(af[m], bfr[n], acc[m][n], 0, 0, 0);
        __syncthreads();
    }

    // epilogue: C/D layout col = lane&15, row = (lane>>4)*4 + r  [m89-verified]
    int colb = bn + wc*64 + (l & 15);
    #pragma unroll
    for (int m = 0; m < 4; ++m) {
        int row0 = bm + wr*64 + m*16 + (l >> 4)*4;
        #pragma unroll
        for (int r = 0; r < 4; ++r) {
            int row = row0 + r;
            int valid = 1;
            if (EPI) valid = get_valid(mask, row, u8);
            #pragma unroll
            for (int n = 0; n < 4; ++n) {
                int cc = colb + n*16;
                float val = acc[m][n][r];
                if (EPI) {
                    val = valid ? resid[(size_t)row*256 + cc] + val : 0.f;
                    ((float*)C)[(size_t)row*256 + cc] = val;
                } else {
                    ((unsigned short*)C)[(size_t)row*256 + cc] = f2bf(val);
                }
            }
        }
    }
}

__global__ __launch_bounds__(256) void gemm_qkv_mfma(
    const unsigned short* __restrict__ xpebf, const unsigned short* __restrict__ xbf,
    const unsigned short* __restrict__ WT,
    unsigned short* __restrict__ q, unsigned short* __restrict__ k,
    unsigned short* __restrict__ v) {
    __shared__ __align__(16) char smem[16384];
    int z = blockIdx.z;
    const unsigned short* A  = (z == 2) ? xbf : xpebf;
    const unsigned short* BT = WT + (size_t)z * 65536;
    unsigned short* C = (z == 0) ? q : (z == 1) ? k : v;
    gemm_mfma_core<0>(A, BT, C, nullptr, nullptr, 0, blockIdx.x*128, blockIdx.y*128, smem);
}

__global__ __launch_bounds__(256) void gemm_out_mfma(
    const unsigned short* __restrict__ aobf, const unsigned short* __restrict__ WT,
    const float* __restrict__ x, const void* __restrict__ mask,
    const int* __restrict__ flag, float* __restrict__ out) {
    __shared__ __align__(16) char smem[16384];
    int u8 = *flag;
    gemm_mfma_core<1>(aobf, WT + (size_t)3 * 65536, out, x, mask, u8,
                      blockIdx.x * 128, blockIdx.y * 128, smem);
}

// ---------------- local attention: one wave per token, bf16 q/k/v ----------------
__global__ __launch_bounds__(256) void attn_kernel(
    const unsigned short* __restrict__ q, const unsigned short* __restrict__ k,
    const unsigned short* __restrict__ v, const int* __restrict__ idx,
    const void* __restrict__ mask, const int* __restrict__ flag,
    unsigned short* __restrict__ aobf) {
    __shared__ int   s_j[4][16];
    __shared__ float s_w[4][16][8];
    int u8 = *flag;
    int wave = threadIdx.x >> 6, lane = threadIdx.x & 63;
    // XCD-chunked swizzle: 4096 blocks -> 512 consecutive blocks per XCD
    int cpx = gridDim.x >> 3;
    int sb = ((int)blockIdx.x & 7) * cpx + ((int)blockIdx.x >> 3);
    int t = sb * 4 + wave;
    int b = t >> 10;
    int sub = lane & 3, nbr = lane >> 2;
    int j = idx[(size_t)t*KNBR + nbr];
    if (lane < 16) s_j[wave][lane] = idx[(size_t)t*KNBR + lane];
    int nv = get_valid(mask, b*NN + j, u8);
    const unsigned short* qb = q + (size_t)t*DD;
    const unsigned short* kb = k + ((size_t)(b*NN + j))*DD;

    float w[8];
    #pragma unroll
    for (int h = 0; h < 8; ++h) {
        bf16x8 qv = *(const bf16x8*)(qb + h*32 + sub*8);
        bf16x8 kv = *(const bf16x8*)(kb + h*32 + sub*8);
        float acc = 0.f;
        #pragma unroll
        for (int e = 0; e < 8; ++e)
            acc += bf2f((unsigned short)qv[e]) * bf2f((unsigned short)kv[e]);
        acc += __shfl_xor(acc, 1);
        acc += __shfl_xor(acc, 2);
        float s = nv ? acc * 0.17677669529663688f : -1e9f;   // 1/sqrt(32)
        float m = s;
        #pragma unroll
        for (int off = 4; off <= 32; off <<= 1) m = fmaxf(m, __shfl_xor(m, off));
        float e = __expf(s - m);
        float sum = e;
        #pragma unroll
        for (int off = 4; off <= 32; off <<= 1) sum += __shfl_xor(sum, off);
        w[h] = e / sum;
    }
    if (sub == 0) {
        #pragma unroll
        for (int h = 0; h < 8; ++h) s_w[wave][nbr][h] = w[h];
    }
    __syncthreads();

    // PV: channel c0 = lane*4 .. +3, head h = lane>>3
    int c0 = lane * 4;
    int h = lane >> 3;
    float o0 = 0.f, o1 = 0.f, o2 = 0.f, o3 = 0.f;
    #pragma unroll
    for (int kk = 0; kk < 16; ++kk) {
        int jj = s_j[wave][kk];
        float wk = s_w[wave][kk][h];
        u16x4 vv = *(const u16x4*)(v + ((size_t)(b*NN + jj))*DD + c0);
        o0 += wk * bf2f(vv[0]);
        o1 += wk * bf2f(vv[1]);
        o2 += wk * bf2f(vv[2]);
        o3 += wk * bf2f(vv[3]);
    }
    u16x4 st;
    st[0] = f2bf(o0); st[1] = f2bf(o1); st[2] = f2bf(o2); st[3] = f2bf(o3);
    *(u16x4*)(aobf + (size_t)t*DD + c0) = st;
}

extern "C" void kernel_launch(void* const* d_in, const int* in_sizes, int n_in,
                              void* d_out, int out_size, void* d_ws, size_t ws_size,
                              hipStream_t stream) {
    const float* x    = (const float*)d_in[0];
    const float* xpos = (const float*)d_in[1];
    const void*  mask = d_in[2];
    const float* Wq   = (const float*)d_in[3];
    const float* Wk   = (const float*)d_in[4];
    const float* Wv   = (const float*)d_in[5];
    const float* Wo   = (const float*)d_in[6];
    float* out = (float*)d_out;
    char*  ws  = (char*)d_ws;
    if (ws_size < WS_NEED) return;

    int*            flag  = (int*)           (ws + OFF_FLAG);
    unsigned short* xpebf = (unsigned short*)(ws + OFF_XPE);
    unsigned short* xbf   = (unsigned short*)(ws + OFF_XBF);
    unsigned short* WT    = (unsigned short*)(ws + OFF_WT);
    unsigned short* q     = (unsigned short*)(ws + OFF_Q);
    unsigned short* k     = (unsigned short*)(ws + OFF_K);
    unsigned short* v     = (unsigned short*)(ws + OFF_V);
    unsigned short* aobf  = (unsigned short*)(ws + OFF_AO);
    int*            idx   = (int*)           (ws + OFF_IDX);

    detect_cvtw_kernel<<<1025, 256, 0, stream>>>((const unsigned*)mask, flag,
                                                 Wq, Wk, Wv, Wo, WT);
    knn_kernel<<<dim3(NN/4, BB), 256, 0, stream>>>(xpos, idx);
    pe_cvt_kernel<<<MM/2, 256, 0, stream>>>(x, xpos, mask, flag, xpebf, xbf);
    gemm_qkv_mfma<<<dim3(128, 2, 3), 256, 0, stream>>>(xpebf, xbf, WT, q, k, v);
    attn_kernel<<<MM/4, 256, 0, stream>>>(q, k, v, idx, mask, flag, aobf);
    gemm_out_mfma<<<dim3(128, 2), 256, 0, stream>>>(aobf, WT, x, mask, flag, out);
}

// Round 8
// 86.848 us; speedup vs baseline: 3.0574x; 1.0593x over previous
//
#include <hip/hip_runtime.h>
#include <math.h>

// Problem constants
#define BB 16
#define NN 1024
#define DD 256
#define HH 8
#define DHH 32
#define KNBR 16
#define MM (BB*NN)   // 16384 tokens

typedef __attribute__((ext_vector_type(8))) short  bf16x8;
typedef __attribute__((ext_vector_type(4))) float  f32x4;
typedef __attribute__((ext_vector_type(2))) unsigned short u16x2;
typedef __attribute__((ext_vector_type(4))) unsigned short u16x4;

// ---------------- workspace layout (bytes) ----------------
#define OFF_FLAG 0
#define OFF_XPE  ((size_t)256)                          // bf16 x+pe (8 MB) — aliased by aobf later
#define OFF_XBF  (OFF_XPE + (size_t)MM*DD*2)            // bf16 x    (8 MB)
#define OFF_WT   (OFF_XBF + (size_t)MM*DD*2)            // bf16 WT[4][256][256] (512 KB)
#define OFF_Q    (OFF_WT  + (size_t)4*DD*DD*2)          // bf16 q (8 MB)
#define OFF_K    (OFF_Q   + (size_t)MM*DD*2)
#define OFF_V    (OFF_K   + (size_t)MM*DD*2)
#define OFF_AO   OFF_XPE                                // bf16 attn-out reuses xpe region
#define OFF_IDX  (OFF_V   + (size_t)MM*DD*2)
#define WS_NEED  (OFF_IDX + (size_t)MM*KNBR*4)

// ---------------- bf16 helpers ----------------
__device__ __forceinline__ float bf2f(unsigned short u) {
    unsigned x = ((unsigned)u) << 16;
    return __builtin_bit_cast(float, x);
}
__device__ __forceinline__ unsigned short f2bf(float f) {
    unsigned x = __builtin_bit_cast(unsigned, f);
    unsigned r = (x + 0x7fffu + ((x >> 16) & 1u)) >> 16;   // RNE
    return (unsigned short)r;
}
__device__ __forceinline__ int mbcnt64(unsigned long long b) {
    // popcount of b restricted to lanes strictly below this lane
    return __builtin_amdgcn_mbcnt_hi((unsigned)(b >> 32),
           __builtin_amdgcn_mbcnt_lo((unsigned)b, 0));
}

__device__ __forceinline__ int get_valid(const void* m, int i, int u8) {
    if (u8) return ((const unsigned char*)m)[i] != 0;
    return ((const unsigned*)m)[i] != 0u;
}

// ---------------- mask format detection (1 block) ----------------
// flag: 0 = 4-byte elements (int32/float32), 1 = 1-byte (uint8 bool)
__global__ __launch_bounds__(256) void detect_kernel(
    const unsigned* __restrict__ mraw, int* __restrict__ flag) {
    __shared__ int s_u8, s_f32;
    if (threadIdx.x == 0) { s_u8 = 0; s_f32 = 0; }
    __syncthreads();
    int u8 = 0, f32 = 0;
    for (int i = threadIdx.x; i < 4096; i += 256) {
        unsigned w = mraw[i];
        if (w == 0x3f800000u) f32 = 1;
        else if (w > 1u) u8 = 1;
    }
    if (u8)  atomicOr(&s_u8, 1);
    if (f32) atomicOr(&s_f32, 1);
    __syncthreads();
    if (threadIdx.x == 0) *flag = (s_f32 ? 0 : (s_u8 ? 1 : 0));
}

// ---------------- fused prep: KNN [0,4096) | cvtW [4096,5120) | PE+cvt [5120,13312) ----
// knn: VALU-bound; pe_cvt: HBM-bound; cvtW: tiny. Disjoint pipes -> co-scheduled
// overlap (m114). knn blocks first (long pole). pe reads flag from detect_kernel.
__global__ __launch_bounds__(256, 8) void prep_fused(
    const float* __restrict__ xpos, int* __restrict__ idxout,
    const float* __restrict__ x, const void* __restrict__ mask,
    const int* __restrict__ flag,
    const float* __restrict__ Wq, const float* __restrict__ Wk,
    const float* __restrict__ Wv, const float* __restrict__ Wo,
    unsigned short* __restrict__ WT,
    unsigned short* __restrict__ xpebf, unsigned short* __restrict__ xbf) {
    __shared__ float4   sp[NN];          // 16 KB (knn)
    __shared__ unsigned scand[4][64];    // 1 KB  (knn)
    int bid = blockIdx.x;
    int tid = threadIdx.x;

    if (bid >= 5120) {
        // ---- PE + bf16 conversion path ----
        int pb = bid - 5120;
        int t = pb * 2 + (tid >> 7);
        int p = tid & 127;
        int u8 = *flag;
        int valid = get_valid(mask, t, u8);
        int half = p >> 6;             // 0 -> y channels [0,128), 1 -> x [128,256)
        int j = p & 63;
        float pos = xpos[(size_t)t*3 + (half ? 0 : 1)];
        float recip = 6.2831853071795864f * exp2f(-(float)j * 0.20762050593045952f);
        float th = pos * recip;
        float s, c;
        __sincosf(th, &s, &c);
        if (!valid) { s = 0.f; c = 0.f; }
        size_t o = (size_t)t*DD + half*128 + 2*j;
        float2 xv = *(const float2*)(x + o);
        u16x2 xb; xb[0] = f2bf(xv.x);     xb[1] = f2bf(xv.y);
        u16x2 xp; xp[0] = f2bf(xv.x + s); xp[1] = f2bf(xv.y + c);
        *(u16x2*)(xbf + o)   = xb;
        *(u16x2*)(xpebf + o) = xp;
        return;
    }
    if (bid >= 4096) {
        // ---- weight convert/transpose path: WT[w][n][k] = bf16(W[k][n]) ----
        int g = bid - 4096;              // 0..1023
        int wsel = g >> 8;               // 0..3
        int kk = g & 255;                // 0..255
        const float* W = (wsel == 0) ? Wq : (wsel == 1) ? Wk : (wsel == 2) ? Wv : Wo;
        WT[(size_t)wsel*65536 + (size_t)tid*256 + kk] = f2bf(W[(size_t)kk*256 + tid]);
        return;
    }

    // ---- KNN path: one wave per query row (proven R7 algorithm) ----
    int nblk = bid & 255;    // 0..255
    int b    = bid >> 8;     // 0..15
    for (int i = tid; i < NN; i += 256) {
        const float* p = xpos + ((size_t)b*NN + i)*3;
        float px = p[0], py = p[1], pz = p[2];
        sp[i] = make_float4(px, py, pz, px*px + py*py + pz*pz);
    }
    __syncthreads();
    int wave = tid >> 6, lane = tid & 63;
    int n = nblk * 4 + wave;
    float4 qp = sp[n];
    float d[16];
    #pragma unroll
    for (int t = 0; t < 16; ++t) {
        float4 pm = sp[lane + 64*t];
        float dot = qp.x*pm.x + qp.y*pm.y + qp.z*pm.z;
        float d2 = qp.w + pm.w - 2.f*dot;              // exact reference formula
        d[t] = fmaxf(d2, 0.f);
    }
    // 1) per-lane min
    float lmin = d[0];
    #pragma unroll
    for (int t = 1; t < 16; ++t) lmin = fminf(lmin, d[t]);
    // 2) bitonic sort 64 lane minima ascending; tau = 16th smallest (>= v16)
    float xs = lmin;
    #pragma unroll
    for (int kk = 2; kk <= 64; kk <<= 1) {
        #pragma unroll
        for (int j = kk >> 1; j >= 1; j >>= 1) {
            float vv = __shfl_xor(xs, j);
            bool up = ((lane & kk) == 0);
            bool lower = ((lane & j) == 0);
            xs = (up == lower) ? fminf(xs, vv) : fmaxf(xs, vv);
        }
    }
    float tau = __shfl(xs, 15);
    // 3) candidate count
    int T = 0;
    #pragma unroll
    for (int t = 0; t < 16; ++t) T += (d[t] <= tau) ? 1 : 0;
    #pragma unroll
    for (int off = 1; off <= 32; off <<= 1) T += __shfl_xor(T, off);

    bool fast = (T <= 64);          // wave-uniform
    if (fast) {
        int base = 0;
        #pragma unroll
        for (int t = 0; t < 16; ++t) {
            bool c = (d[t] <= tau);
            unsigned long long bb = __ballot(c);
            if (c) scand[wave][base + mbcnt64(bb)] = __builtin_bit_cast(unsigned, d[t]);
            base += (int)__popcll(bb);
        }
    }
    __syncthreads();   // all 4 knn waves reach this regardless of 'fast'

    int out_base = (b*NN + n) * KNBR;
    if (fast) {
        unsigned key = (lane < T) ? scand[wave][lane] : 0xFFFFFFFFu;
        // bitonic sort 64 u32 values ascending (d2>=0: u32 order == f32 order)
        #pragma unroll
        for (int kk = 2; kk <= 64; kk <<= 1) {
            #pragma unroll
            for (int j = kk >> 1; j >= 1; j >>= 1) {
                unsigned vv = (unsigned)__shfl_xor((int)key, j);
                bool up = ((lane & kk) == 0);
                bool lower = ((lane & j) == 0);
                bool takemin = (up == lower);
                key = (takemin == (key < vv)) ? key : vv;
            }
        }
        unsigned tau2 = (unsigned)__shfl((int)key, 15);   // exact v16
        int c1 = (int)__popcll(__ballot(key < tau2));
        // emit: strict-smaller, then lowest-index ties at v16 (index-exact)
        int lt_base = 0, eq_seen = 0;
        #pragma unroll
        for (int t = 0; t < 16; ++t) {
            unsigned du = __builtin_bit_cast(unsigned, d[t]);
            bool lt = du < tau2;
            bool eq = du == tau2;
            unsigned long long blt = __ballot(lt);
            unsigned long long beq = __ballot(eq);
            if (lt) idxout[out_base + lt_base + mbcnt64(blt)] = lane + 64*t;
            int er = eq_seen + mbcnt64(beq);
            if (eq && (c1 + er) < KNBR) idxout[out_base + c1 + er] = lane + 64*t;
            lt_base += (int)__popcll(blt);
            eq_seen += (int)__popcll(beq);
        }
    } else {
        // exact iterative fallback (proven R3 path)
        #pragma unroll 1
        for (int it = 0; it < KNBR; ++it) {
            float bd = 3.4e38f; int bm = 1 << 30;
            #pragma unroll
            for (int t = 0; t < 16; ++t)
                if (d[t] < bd) { bd = d[t]; bm = lane + 64*t; }
            #pragma unroll
            for (int off = 32; off >= 1; off >>= 1) {
                float od = __shfl_xor(bd, off);
                int   om = __shfl_xor(bm, off);
                if (od < bd || (od == bd && om < bm)) { bd = od; bm = om; }
            }
            if (lane == 0) idxout[out_base + it] = bm;
            int sel = bm >> 6;
            int mine = ((bm & 63) == lane);
            #pragma unroll
            for (int t = 0; t < 16; ++t)
                if (mine && t == sel) d[t] = 3.4e38f;
        }
    }
}

// ---------------- bf16 MFMA GEMM core: C[M,256] = A[M,256] @ W[256,256] ----------------
// Tile 128x128, BK=32, 4 waves, each wave 64x64 = 4x4 fragments of 16x16x32.
template<int EPI>
__device__ __forceinline__ void gemm_mfma_core(
    const unsigned short* __restrict__ A, const unsigned short* __restrict__ BT,
    void* __restrict__ C, const float* __restrict__ resid,
    const void* __restrict__ mask, int u8, int bm, int bn, char* smem) {
    unsigned short (*As)[32] = (unsigned short (*)[32])smem;
    unsigned short (*Bs)[32] = (unsigned short (*)[32])(smem + 8192);
    int tid = threadIdx.x;
    int w = tid >> 6, l = tid & 63;
    int wr = w >> 1, wc = w & 1;

    f32x4 acc[4][4] = {};

    for (int kt = 0; kt < 8; ++kt) {
        #pragma unroll
        for (int j = 0; j < 2; ++j) {
            int c  = (w + j*4)*64 + l;        // 0..511
            int row = c >> 2;                 // 0..127
            int cb  = (c & 3) * 16;           // byte col within 64B row
            const char* ga = (const char*)A + ((size_t)(bm + row)*256 + kt*32)*2 + cb;
            char* la = (char*)As + (size_t)(w + j*4)*1024;   // wave-uniform dest
            __builtin_amdgcn_global_load_lds(
                (const __attribute__((address_space(1))) unsigned*)ga,
                (__attribute__((address_space(3))) unsigned*)la, 16, 0, 0);
            const char* gb = (const char*)BT + ((size_t)(bn + row)*256 + kt*32)*2 + cb;
            char* lb = (char*)Bs + (size_t)(w + j*4)*1024;
            __builtin_amdgcn_global_load_lds(
                (const __attribute__((address_space(1))) unsigned*)gb,
                (__attribute__((address_space(3))) unsigned*)lb, 16, 0, 0);
        }
        __syncthreads();

        bf16x8 af[4], bfr[4];
        #pragma unroll
        for (int m = 0; m < 4; ++m)
            af[m] = *(const bf16x8*)&As[wr*64 + m*16 + (l & 15)][(l >> 4) * 8];
        #pragma unroll
        for (int n = 0; n < 4; ++n)
            bfr[n] = *(const bf16x8*)&Bs[wc*64 + n*16 + (l & 15)][(l >> 4) * 8];
        #pragma unroll
        for (int m = 0; m < 4; ++m)
            #pragma unroll
            for (int n = 0; n < 4; ++n)
                acc[m][n] = __builtin_amdgcn_mfma_f32_16x16x32_bf16(af[m], bfr[n], acc[m][n], 0, 0, 0);
        __syncthreads();
    }

    // epilogue: C/D layout col = lane&15, row = (lane>>4)*4 + r  [m89-verified]
    int colb = bn + wc*64 + (l & 15);
    #pragma unroll
    for (int m = 0; m < 4; ++m) {
        int row0 = bm + wr*64 + m*16 + (l >> 4)*4;
        #pragma unroll
        for (int r = 0; r < 4; ++r) {
            int row = row0 + r;
            int valid = 1;
            if (EPI) valid = get_valid(mask, row, u8);
            #pragma unroll
            for (int n = 0; n < 4; ++n) {
                int cc = colb + n*16;
                float val = acc[m][n][r];
                if (EPI) {
                    val = valid ? resid[(size_t)row*256 + cc] + val : 0.f;
                    ((float*)C)[(size_t)row*256 + cc] = val;
                } else {
                    ((unsigned short*)C)[(size_t)row*256 + cc] = f2bf(val);
                }
            }
        }
    }
}

__global__ __launch_bounds__(256) void gemm_qkv_mfma(
    const unsigned short* __restrict__ xpebf, const unsigned short* __restrict__ xbf,
    const unsigned short* __restrict__ WT,
    unsigned short* __restrict__ q, unsigned short* __restrict__ k,
    unsigned short* __restrict__ v) {
    __shared__ __align__(16) char smem[16384];
    int z = blockIdx.z;
    const unsigned short* A  = (z == 2) ? xbf : xpebf;
    const unsigned short* BT = WT + (size_t)z * 65536;
    unsigned short* C = (z == 0) ? q : (z == 1) ? k : v;
    gemm_mfma_core<0>(A, BT, C, nullptr, nullptr, 0, blockIdx.x*128, blockIdx.y*128, smem);
}

__global__ __launch_bounds__(256) void gemm_out_mfma(
    const unsigned short* __restrict__ aobf, const unsigned short* __restrict__ WT,
    const float* __restrict__ x, const void* __restrict__ mask,
    const int* __restrict__ flag, float* __restrict__ out) {
    __shared__ __align__(16) char smem[16384];
    int u8 = *flag;
    gemm_mfma_core<1>(aobf, WT + (size_t)3 * 65536, out, x, mask, u8,
                      blockIdx.x * 128, blockIdx.y * 128, smem);
}

// ---------------- local attention: one wave per token, bf16 q/k/v ----------------
__global__ __launch_bounds__(256) void attn_kernel(
    const unsigned short* __restrict__ q, const unsigned short* __restrict__ k,
    const unsigned short* __restrict__ v, const int* __restrict__ idx,
    const void* __restrict__ mask, const int* __restrict__ flag,
    unsigned short* __restrict__ aobf) {
    __shared__ int   s_j[4][16];
    __shared__ float s_w[4][16][8];
    int u8 = *flag;
    int wave = threadIdx.x >> 6, lane = threadIdx.x & 63;
    // XCD-chunked swizzle: 4096 blocks -> 512 consecutive blocks per XCD
    int cpx = gridDim.x >> 3;
    int sb = ((int)blockIdx.x & 7) * cpx + ((int)blockIdx.x >> 3);
    int t = sb * 4 + wave;
    int b = t >> 10;
    int sub = lane & 3, nbr = lane >> 2;
    int j = idx[(size_t)t*KNBR + nbr];
    if (lane < 16) s_j[wave][lane] = idx[(size_t)t*KNBR + lane];
    int nv = get_valid(mask, b*NN + j, u8);
    const unsigned short* qb = q + (size_t)t*DD;
    const unsigned short* kb = k + ((size_t)(b*NN + j))*DD;

    float w[8];
    #pragma unroll
    for (int h = 0; h < 8; ++h) {
        bf16x8 qv = *(const bf16x8*)(qb + h*32 + sub*8);
        bf16x8 kv = *(const bf16x8*)(kb + h*32 + sub*8);
        float acc = 0.f;
        #pragma unroll
        for (int e = 0; e < 8; ++e)
            acc += bf2f((unsigned short)qv[e]) * bf2f((unsigned short)kv[e]);
        acc += __shfl_xor(acc, 1);
        acc += __shfl_xor(acc, 2);
        float s = nv ? acc * 0.17677669529663688f : -1e9f;   // 1/sqrt(32)
        float m = s;
        #pragma unroll
        for (int off = 4; off <= 32; off <<= 1) m = fmaxf(m, __shfl_xor(m, off));
        float e = __expf(s - m);
        float sum = e;
        #pragma unroll
        for (int off = 4; off <= 32; off <<= 1) sum += __shfl_xor(sum, off);
        w[h] = e / sum;
    }
    if (sub == 0) {
        #pragma unroll
        for (int h = 0; h < 8; ++h) s_w[wave][nbr][h] = w[h];
    }
    __syncthreads();

    // PV: channel c0 = lane*4 .. +3, head h = lane>>3
    int c0 = lane * 4;
    int h = lane >> 3;
    float o0 = 0.f, o1 = 0.f, o2 = 0.f, o3 = 0.f;
    #pragma unroll
    for (int kk = 0; kk < 16; ++kk) {
        int jj = s_j[wave][kk];
        float wk = s_w[wave][kk][h];
        u16x4 vv = *(const u16x4*)(v + ((size_t)(b*NN + jj))*DD + c0);
        o0 += wk * bf2f(vv[0]);
        o1 += wk * bf2f(vv[1]);
        o2 += wk * bf2f(vv[2]);
        o3 += wk * bf2f(vv[3]);
    }
    u16x4 st;
    st[0] = f2bf(o0); st[1] = f2bf(o1); st[2] = f2bf(o2); st[3] = f2bf(o3);
    *(u16x4*)(aobf + (size_t)t*DD + c0) = st;
}

extern "C" void kernel_launch(void* const* d_in, const int* in_sizes, int n_in,
                              void* d_out, int out_size, void* d_ws, size_t ws_size,
                              hipStream_t stream) {
    const float* x    = (const float*)d_in[0];
    const float* xpos = (const float*)d_in[1];
    const void*  mask = d_in[2];
    const float* Wq   = (const float*)d_in[3];
    const float* Wk   = (const float*)d_in[4];
    const float* Wv   = (const float*)d_in[5];
    const float* Wo   = (const float*)d_in[6];
    float* out = (float*)d_out;
    char*  ws  = (char*)d_ws;
    if (ws_size < WS_NEED) return;

    int*            flag  = (int*)           (ws + OFF_FLAG);
    unsigned short* xpebf = (unsigned short*)(ws + OFF_XPE);
    unsigned short* xbf   = (unsigned short*)(ws + OFF_XBF);
    unsigned short* WT    = (unsigned short*)(ws + OFF_WT);
    unsigned short* q     = (unsigned short*)(ws + OFF_Q);
    unsigned short* k     = (unsigned short*)(ws + OFF_K);
    unsigned short* v     = (unsigned short*)(ws + OFF_V);
    unsigned short* aobf  = (unsigned short*)(ws + OFF_AO);
    int*            idx   = (int*)           (ws + OFF_IDX);

    detect_kernel<<<1, 256, 0, stream>>>((const unsigned*)mask, flag);
    prep_fused<<<13312, 256, 0, stream>>>(xpos, idx, x, mask, flag,
                                          Wq, Wk, Wv, Wo, WT, xpebf, xbf);
    gemm_qkv_mfma<<<dim3(128, 2, 3), 256, 0, stream>>>(xpebf, xbf, WT, q, k, v);
    attn_kernel<<<MM/4, 256, 0, stream>>>(q, k, v, idx, mask, flag, aobf);
    gemm_out_mfma<<<dim3(128, 2), 256, 0, stream>>>(aobf, WT, x, mask, flag, out);
}